// Round 1
// 499.047 us; speedup vs baseline: 1.1449x; 1.1449x over previous
//
#include <hip/hip_runtime.h>
#include <math.h>

#define B_ 4
#define C_ 256
#define RES_ 128
#define HW_ 16384
#define WF_ 65
#define F_ 8320
#define FP_ 2880   // packed masked-freq grid: 72 rows x 40 cols (covers runtime 71x36)

typedef __attribute__((ext_vector_type(8))) short bf16x8;
typedef __attribute__((ext_vector_type(16))) float f32x16;

__device__ __forceinline__ int brev7(int j){ return (int)(__brev((unsigned)j) >> 25); }
__device__ __forceinline__ int brev6(int j){ return (int)(__brev((unsigned)j) >> 26); }

__device__ __forceinline__ short f2bf(float f){
  unsigned u = __float_as_uint(f);
  unsigned r = (u + 0x7FFFu + ((u>>16)&1u)) >> 16;
  return (short)r;
}

__device__ __forceinline__ bf16x8 lds_frag(const short* p){
  union { bf16x8 v; int2 d[2]; } u;
  u.d[0] = *(const int2*)p;
  u.d[1] = *(const int2*)(p+4);
  return u.v;
}
__device__ __forceinline__ void lds_store8(short* p, bf16x8 v){
  union { bf16x8 v; int2 d[2]; } u; u.v = v;
  *(int2*)p = u.d[0]; *(int2*)(p+4) = u.d[1];
}

// ---- band id, bit-exact vs numpy float32 ----
__device__ __forceinline__ int band_of(int row, int col){
  float yy = __fdiv_rn((float)row, 127.0f);
  float xx = __fdiv_rn((float)col, 64.0f);
  float rr = __fsqrt_rn(__fadd_rn(__fmul_rn(yy,yy), __fmul_rn(xx,xx)));
  float rm = __fadd_rn(__fsqrt_rn(2.0f), 1e-8f);
  float rn = __fdiv_rn(rr, rm);
  int b = (int)floorf(__fmul_rn(rn, 6.0f));
  return b > 5 ? 5 : b;
}

__device__ __forceinline__ float sigmoidf_(float v){ return 1.0f/(1.0f+expf(-v)); }

// ---- in-LDS radix-2 DIF FFT, length 128 (cols kernels) ----
template<int SGN, int NROWS>
__device__ __forceinline__ void fft128_lds(float2* buf, int rstride, int tid, const float2* tw){
  const int total = NROWS*64;
  #pragma unroll
  for (int stage=0; stage<7; stage++){
    int half = 64 >> stage;
    __syncthreads();
    for (int idx = tid; idx < total; idx += 256){
      int row = idx % NROWS;
      int t   = idx / NROWS;
      int j   = t & (half-1);
      int i0  = ((t >> (6-stage)) << (7-stage)) + j;
      int i1  = i0 + half;
      float2* rb = buf + row*rstride;
      float2 a = rb[i0], b = rb[i1];
      float2 w = tw[j << stage];
      float dx = a.x - b.x, dy = a.y - b.y;
      rb[i0] = make_float2(a.x+b.x, a.y+b.y);
      float ws = (SGN < 0) ? -w.y : w.y;
      rb[i1] = make_float2(dx*w.x - dy*ws, dx*ws + dy*w.x);
    }
  }
  __syncthreads();
}

// ---- in-LDS radix-2 DIF FFT, length 64 (row kernels, half-length real trick) ----
// tw is the SAME e^{+2*pi*i*j/128} table; 64-pt twiddle j -> tw[2j].
template<int SGN, int NROWS>
__device__ __forceinline__ void fft64_lds(float2* buf, int rstride, int tid, const float2* tw){
  const int total = NROWS*32;
  #pragma unroll
  for (int stage=0; stage<6; stage++){
    int half = 32 >> stage;
    __syncthreads();
    for (int idx = tid; idx < total; idx += 256){
      int row = idx & (NROWS-1);
      int t   = idx / NROWS;
      int j   = t & (half-1);
      int i0  = ((t >> (5-stage)) << (6-stage)) + j;
      int i1  = i0 + half;
      float2* rb = buf + row*rstride;
      float2 a = rb[i0], b = rb[i1];
      float2 w = tw[j << (stage+1)];
      float dx = a.x - b.x, dy = a.y - b.y;
      rb[i0] = make_float2(a.x+b.x, a.y+b.y);
      float ws = (SGN < 0) ? -w.y : w.y;
      rb[i1] = make_float2(dx*w.x - dy*ws, dx*ws + dy*w.x);
    }
  }
  __syncthreads();
}

// ---- (B,HW,C) -> (B,C,HW) transpose ----
__global__ __launch_bounds__(1024) void k_transpose(const float* __restrict__ x, float* __restrict__ x2){
  __shared__ float tile[64][65];
  int b = blockIdx.z;
  int hw0 = blockIdx.x*64, c0 = blockIdx.y*64;
  int tx = threadIdx.x, ty = threadIdx.y;
  #pragma unroll
  for (int i=0;i<4;i++){
    int hw = hw0 + ty + i*16;
    tile[ty+i*16][tx] = x[((size_t)b*HW_ + hw)*C_ + c0 + tx];
  }
  __syncthreads();
  #pragma unroll
  for (int i=0;i<4;i++){
    int c = c0 + ty + i*16;
    x2[((size_t)b*C_ + c)*HW_ + hw0 + tx] = tile[tx][ty+i*16];
  }
}

// ---- counts + band-id table ----
__global__ __launch_bounds__(256) void k_counts(float* __restrict__ counts, unsigned char* __restrict__ bid){
  int tid = threadIdx.x;
  float acc[6] = {0,0,0,0,0,0};
  for (int f = tid; f < F_; f += 256){
    int row = f / WF_, col = f - row*WF_;
    int bnd = band_of(row, col);
    bid[f] = (unsigned char)bnd;
    #pragma unroll
    for (int n=0;n<6;n++) acc[n] += (bnd==n) ? 1.0f : 0.0f;
  }
  __shared__ float red[6][256];
  #pragma unroll
  for (int n=0;n<6;n++) red[n][tid] = acc[n];
  __syncthreads();
  for (int s=128; s>0; s>>=1){
    if (tid < s){
      #pragma unroll
      for (int n=0;n<6;n++) red[n][tid] += red[n][tid+s];
    }
    __syncthreads();
  }
  if (tid < 6) counts[tid] = fmaxf(red[tid][0], 1.0f);
}

// ---- convert W matrices to bf16 planes ----
__global__ __launch_bounds__(256) void k_wbf16(const float* __restrict__ wre, const float* __restrict__ wim,
                                               const float* __restrict__ lw,
                                               short* __restrict__ Wre, short* __restrict__ Wim,
                                               short* __restrict__ WL){
  int c = blockIdx.x, tid = threadIdx.x, plane = blockIdx.y;
  int idx = c*C_ + tid;
  if (plane == 0)      Wre[idx] = f2bf(wre[idx]);
  else if (plane == 1) Wim[idx] = f2bf(wim[idx]);
  else                 WL[idx]  = f2bf(lw[idx]);
}

// ---- forward row rFFT via 64-pt complex FFT: x2 -> X1 (unnormalized 128-pt r2c) ----
__global__ __launch_bounds__(256) void k_fwd_rows(const float* __restrict__ x2, float2* __restrict__ X1){
  __shared__ float2 buf[32*65];
  __shared__ float2 tw[64];
  int tid = threadIdx.x;
  if (tid < 64){ float s,c; sincosf(6.283185307179586f*(float)tid/128.0f,&s,&c); tw[tid]=make_float2(c,s); }
  int slice = blockIdx.x >> 2;
  int r0 = (blockIdx.x & 3) * 32;
  const float4* src = (const float4*)(x2 + (size_t)slice*HW_ + (size_t)r0*128);
  #pragma unroll
  for (int q=0; q<4; q++){
    int f4 = tid + 256*q;
    float4 v = src[f4];
    int pos = f4*4;
    int row = pos >> 7, i = pos & 127;
    float2* rb = buf + row*65 + (i >> 1);
    rb[0] = make_float2(v.x, v.y);     // y[m]   = x[2m] + i x[2m+1]
    rb[1] = make_float2(v.z, v.w);
  }
  fft64_lds<-1,32>(buf, 65, tid, tw);
  float2* dst = X1 + (size_t)slice*F_ + (size_t)r0*WF_;
  for (int p = tid; p < 32*WF_; p += 256){
    int row = p / WF_, k = p - row*WF_;
    const float2* rb = buf + row*65;
    float2 Yk = rb[brev6(k & 63)];
    float2 Ym = rb[brev6((64 - k) & 63)];
    float cs, sn;
    if (k == 64){ cs = -1.0f; sn = 0.0f; }
    else { float2 w = tw[k]; cs = w.x; sn = w.y; }
    float sx = Yk.x + Ym.x, sy = Yk.y - Ym.y;
    float dx = Yk.x - Ym.x, dy = Yk.y + Ym.y;
    // X[k] = 0.5*(s - i*e^{-i th}*d)
    dst[p] = make_float2(0.5f*(sx - sn*dx + cs*dy), 0.5f*(sy - cs*dx - sn*dy));
  }
}

// ---- forward col FFT + ortho scale + band-gate ----
__global__ __launch_bounds__(256) void k_fwd_cols_gate(const float2* __restrict__ X1, float2* __restrict__ Xf,
                                                       const float* __restrict__ counts, const unsigned char* __restrict__ bid,
                                                       const float* __restrict__ w1, const float* __restrict__ b1,
                                                       const float* __restrict__ w2, const float* __restrict__ b2,
                                                       float* __restrict__ alpha){
  __shared__ float2 cbuf[13*129];
  __shared__ float2 tw[64];
  __shared__ float red[6][256];
  __shared__ float means[6], h[128];
  int tid = threadIdx.x;
  if (tid < 64){ float s,c; sincosf(6.283185307179586f*(float)tid/128.0f,&s,&c); tw[tid]=make_float2(c,s); }
  int slice = blockIdx.x;
  const float2* xin = X1 + (size_t)slice*F_;
  float2* xout = Xf + (size_t)slice*F_;
  float acc[6] = {0,0,0,0,0,0};
  for (int chunk=0; chunk<5; chunk++){
    int c0 = chunk*13;
    __syncthreads();
    for (int p = tid; p < 13*128; p += 256){
      int y = p / 13, col = p - y*13;
      cbuf[col*129 + y] = xin[y*WF_ + c0 + col];
    }
    fft128_lds<-1,13>(cbuf, 129, tid, tw);
    for (int p = tid; p < 13*128; p += 256){
      int ky = p / 13, col = p - ky*13, kx = c0 + col;
      float2 v = cbuf[col*129 + brev7(ky)];
      v.x *= 0.0078125f; v.y *= 0.0078125f;
      int f = ky*WF_ + kx;
      xout[f] = v;
      float m = __fsqrt_rn(v.x*v.x + v.y*v.y);
      int bb = (int)bid[f];
      #pragma unroll
      for (int n=0;n<6;n++) acc[n] += (bb==n) ? m : 0.0f;
    }
  }
  __syncthreads();
  #pragma unroll
  for (int n=0;n<6;n++) red[n][tid] = acc[n];
  __syncthreads();
  for (int s=128; s>0; s>>=1){
    if (tid < s){
      #pragma unroll
      for (int n=0;n<6;n++) red[n][tid] += red[n][tid+s];
    }
    __syncthreads();
  }
  if (tid < 6) means[tid] = red[tid][0] / (counts[tid] + 1e-6f);
  __syncthreads();
  if (tid < 128){
    float hv = b1[tid];
    #pragma unroll
    for (int n=0;n<6;n++) hv += means[n]*w1[tid*6+n];
    h[tid] = fmaxf(hv, 0.0f);
  }
  __syncthreads();
  if (tid < 6){
    float o = b2[tid];
    for (int j=0;j<128;j++) o += h[j]*w2[tid*128+j];
    alpha[slice*6 + tid] = sigmoidf_(o);
  }
}

// ---- pack+transpose Xf (static 72x40 region) -> Xt planes [b][fp][d] bf16 ----
__global__ __launch_bounds__(256) void k_xt(const float2* __restrict__ Xf,
                                            short* __restrict__ XtRe, short* __restrict__ XtIm){
  __shared__ float2 tile[40][129];
  int tid = threadIdx.x;
  int ky = blockIdx.x, d0 = blockIdx.y*128, b = blockIdx.z;
  const float2* xb = Xf + ((size_t)(b*C_ + d0))*F_ + ky*WF_;
  #pragma unroll
  for (int i=0;i<20;i++){
    int p = tid + i*256;
    int d = p / 40, kx = p - d*40;
    tile[kx][d] = xb[(size_t)d*F_ + kx];
  }
  __syncthreads();
  #pragma unroll
  for (int i=0;i<20;i++){
    int p = tid + i*256;
    int kx = p >> 7, d = p & 127;
    float2 v = tile[kx][d];
    size_t o = ((size_t)b*FP_ + ky*40 + kx)*C_ + d0 + d;
    XtRe[o] = f2bf(v.x);
    XtIm[o] = f2bf(v.y);
  }
}

// ---- MFMA complex channel mix: mappedP[c][fp] = sum_d W[c][d] * X[fp][d] ----
__global__ __launch_bounds__(256) void k_mix_mfma(const short* __restrict__ Wre, const short* __restrict__ Wim,
                                                  const short* __restrict__ XtRe, const short* __restrict__ XtIm,
                                                  const float* __restrict__ kxp, const float* __restrict__ kyp,
                                                  float2* __restrict__ mappedP){
  __shared__ short Are[64][36], Aim[64][36], Bre[64][36], Bim[64][36];
  int tid = threadIdx.x;
  int fp0 = blockIdx.x*64, c0 = blockIdx.y*64, b = blockIdx.z;
  int lane = tid & 63, w = tid >> 6;
  int mt = (w >> 1)*32, nt = (w & 1)*32;
  f32x16 accre = {0.f,0.f,0.f,0.f,0.f,0.f,0.f,0.f,0.f,0.f,0.f,0.f,0.f,0.f,0.f,0.f};
  f32x16 accim = {0.f,0.f,0.f,0.f,0.f,0.f,0.f,0.f,0.f,0.f,0.f,0.f,0.f,0.f,0.f,0.f};
  const short* xrb = XtRe + ((size_t)b*FP_ + fp0)*C_;
  const short* xib = XtIm + ((size_t)b*FP_ + fp0)*C_;
  int row4 = tid >> 2, part = tid & 3;
  for (int kc=0; kc<8; kc++){
    int d0 = kc*32;
    __syncthreads();
    lds_store8(&Are[row4][part*8], *(const bf16x8*)&Wre[(c0+row4)*C_ + d0 + part*8]);
    lds_store8(&Aim[row4][part*8], *(const bf16x8*)&Wim[(c0+row4)*C_ + d0 + part*8]);
    lds_store8(&Bre[row4][part*8], *(const bf16x8*)&xrb[(size_t)row4*C_ + d0 + part*8]);
    lds_store8(&Bim[row4][part*8], *(const bf16x8*)&xib[(size_t)row4*C_ + d0 + part*8]);
    __syncthreads();
    #pragma unroll
    for (int ks=0; ks<2; ks++){
      int koff = ks*16 + (lane>>5)*8;
      bf16x8 are = lds_frag(&Are[mt + (lane&31)][koff]);
      bf16x8 aim = lds_frag(&Aim[mt + (lane&31)][koff]);
      bf16x8 bre = lds_frag(&Bre[nt + (lane&31)][koff]);
      bf16x8 bim = lds_frag(&Bim[nt + (lane&31)][koff]);
      bf16x8 naim;
      { union { bf16x8 v; unsigned u[4]; } t1, t2; t1.v = aim;
        #pragma unroll
        for (int j=0;j<4;j++) t2.u[j] = t1.u[j] ^ 0x80008000u;
        naim = t2.v; }
      accre = __builtin_amdgcn_mfma_f32_32x32x16_bf16(are,  bre, accre, 0,0,0);
      accre = __builtin_amdgcn_mfma_f32_32x32x16_bf16(naim, bim, accre, 0,0,0);
      accim = __builtin_amdgcn_mfma_f32_32x32x16_bf16(are,  bim, accim, 0,0,0);
      accim = __builtin_amdgcn_mfma_f32_32x32x16_bf16(aim,  bre, accim, 0,0,0);
    }
  }
  float rowlim = floorf(sigmoidf_(kxp[0])*128.0f);
  float collim = floorf(sigmoidf_(kyp[0])*65.0f);
  int n = fp0 + nt + (lane & 31);
  int ky = n / 40, kx = n - ky*40;
  bool live = ((float)ky < rowlim) && ((float)kx < collim);
  #pragma unroll
  for (int reg=0; reg<16; reg++){
    int r = (reg & 3) + 8*(reg >> 2) + 4*(lane >> 5);
    int c = c0 + mt + r;
    if (live)
      mappedP[((size_t)(b*C_ + c))*FP_ + n] = make_float2(accre[reg], accim[reg]);
  }
}

// ---- MFMA pointwise: xcs[c][hw] = sum_d lin_w[c][d] * x[hw][d] + lin_b[c] ----
__global__ __launch_bounds__(256) void k_pw_mfma(const float* __restrict__ x, const short* __restrict__ WL,
                                                  const float* __restrict__ lb, float* __restrict__ xcs){
  __shared__ short As[64][36], Bs[64][36];
  int tid = threadIdx.x;
  int hw0 = blockIdx.x*64, c0 = blockIdx.y*64, b = blockIdx.z;
  int lane = tid & 63, w = tid >> 6;
  int mt = (w >> 1)*32, nt = (w & 1)*32;
  f32x16 acc = {0.f,0.f,0.f,0.f,0.f,0.f,0.f,0.f,0.f,0.f,0.f,0.f,0.f,0.f,0.f,0.f};
  const float* xb = x + ((size_t)b*HW_ + hw0)*C_;
  int row4 = tid >> 2, part = tid & 3;
  for (int kc=0; kc<8; kc++){
    int d0 = kc*32;
    __syncthreads();
    lds_store8(&As[row4][part*8], *(const bf16x8*)&WL[(c0+row4)*C_ + d0 + part*8]);
    {
      const float* src = &xb[(size_t)row4*C_ + d0 + part*8];
      float4 va = *(const float4*)src;
      float4 vb = *(const float4*)(src+4);
      bf16x8 bv;
      bv[0]=f2bf(va.x); bv[1]=f2bf(va.y); bv[2]=f2bf(va.z); bv[3]=f2bf(va.w);
      bv[4]=f2bf(vb.x); bv[5]=f2bf(vb.y); bv[6]=f2bf(vb.z); bv[7]=f2bf(vb.w);
      lds_store8(&Bs[row4][part*8], bv);
    }
    __syncthreads();
    #pragma unroll
    for (int ks=0; ks<2; ks++){
      int koff = ks*16 + (lane>>5)*8;
      bf16x8 a  = lds_frag(&As[mt + (lane&31)][koff]);
      bf16x8 bb = lds_frag(&Bs[nt + (lane&31)][koff]);
      acc = __builtin_amdgcn_mfma_f32_32x32x16_bf16(a, bb, acc, 0,0,0);
    }
  }
  int n = hw0 + nt + (lane & 31);
  #pragma unroll
  for (int reg=0; reg<16; reg++){
    int r = (reg & 3) + 8*(reg >> 2) + 4*(lane >> 5);
    int c = c0 + mt + r;
    xcs[((size_t)(b*C_ + c))*HW_ + n] = acc[reg] + lb[c];
  }
}

// ---- inverse col FFT with fused alpha-blend; Y1 written in place into Xf region ----
__global__ __launch_bounds__(256) void k_inv_cols(float2* __restrict__ XfY, const float2* __restrict__ mappedP,
                                                  const float* __restrict__ alpha, const unsigned char* __restrict__ bid,
                                                  const float* __restrict__ kxp, const float* __restrict__ kyp){
  __shared__ float2 cbuf[13*129];
  __shared__ float2 tw[64];
  __shared__ float al[6];
  int tid = threadIdx.x;
  int chunk = blockIdx.x, slice = blockIdx.y;
  int c0 = chunk*13;
  if (tid < 64){ float s,c; sincosf(6.283185307179586f*(float)tid/128.0f,&s,&c); tw[tid]=make_float2(c,s); }
  if (tid < 6) al[tid] = alpha[slice*6 + tid];
  float rowlim = floorf(sigmoidf_(kxp[0])*128.0f);
  float collim = floorf(sigmoidf_(kyp[0])*65.0f);
  __syncthreads();
  float2* xfb = XfY + (size_t)slice*F_;
  const float2* mpb = mappedP + (size_t)slice*FP_;
  for (int p = tid; p < 13*128; p += 256){
    int ky = p / 13, col = p - ky*13, kx = c0 + col;
    int f = ky*WF_ + kx;
    float a = al[(int)bid[f]];
    bool inm = ((float)ky < rowlim) && ((float)kx < collim);
    float2 v;
    if (inm){ v = mpb[ky*40 + kx]; v.x *= a; v.y *= a; }
    else    { v = xfb[f]; float om = 1.0f - a; v.x *= om; v.y *= om; }
    cbuf[col*129 + ky] = v;
  }
  fft128_lds<1,13>(cbuf, 129, tid, tw);
  for (int p = tid; p < 13*128; p += 256){
    int y = p / 13, col = p - y*13;
    xfb[y*WF_ + c0 + col] = cbuf[col*129 + brev7(y)];
  }
}

// ---- inverse row c2r via 64-pt complex FFT + fused depthwise 3x3 conv + xcs -> sbuf ----
__global__ __launch_bounds__(256) void k_inv_rows(const float2* __restrict__ Y1, const float* __restrict__ xcs,
                                                  const float* __restrict__ x2, const float* __restrict__ cw,
                                                  float* __restrict__ sbuf){
  __shared__ float2 buf[32*65];
  __shared__ float2 tw[64];
  __shared__ float ct[34*128];
  int tid = threadIdx.x;
  if (tid < 64){ float s,c; sincosf(6.283185307179586f*(float)tid/128.0f,&s,&c); tw[tid]=make_float2(c,s); }
  int slice = blockIdx.x >> 2;
  int ch = slice & 255;
  int r0 = (blockIdx.x & 3) * 32;
  const float* img = x2 + (size_t)slice*HW_;
  #pragma unroll
  for (int q=0;q<17;q++){
    int p = tid + q*256;
    int row = p >> 7, xx = p & 127;
    int sr = r0 - 1 + row;
    ct[p] = ((unsigned)sr < 128u) ? img[sr*128+xx] : 0.0f;
  }
  float w9[9];
  #pragma unroll
  for (int k=0;k<9;k++) w9[k] = cw[ch*9+k];
  const float2* src = Y1 + (size_t)slice*F_ + (size_t)r0*WF_;
  __syncthreads();   // tw ready before recombination reads it
  // Y[k] = 0.5*(X[k]+conj(X[64-k])) + 0.5*i*e^{+i th_k}*(X[k]-conj(X[64-k])), th_k = 2 pi k/128
  for (int p = tid; p < 32*64; p += 256){
    int row = p >> 6, k = p & 63;
    const float2* rs = src + row*WF_;
    float2 a = rs[k];
    float2 b = rs[64 - k];
    if (k == 0){ a.y = 0.0f; b.y = 0.0f; }   // force Im(X[0]) = Im(X[64]) = 0
    float2 w = tw[k];
    float sx = a.x + b.x, sy = a.y - b.y;
    float dx = a.x - b.x, dy = a.y + b.y;
    buf[row*65 + k] = make_float2(0.5f*(sx - w.y*dx - w.x*dy),
                                  0.5f*(sy + w.x*dx - w.y*dy));
  }
  fft64_lds<1,32>(buf, 65, tid, tw);
  size_t gbase = (size_t)slice*HW_ + (size_t)r0*128;
  for (int p = tid; p < 32*64; p += 256){
    int row = p >> 6, m = p & 63;
    float2 z = buf[row*65 + brev6(m)];   // x[2m] = Re/64, x[2m+1] = Im/64
    int xx = m << 1;
    float c0 = 0.0f, c1 = 0.0f;
    #pragma unroll
    for (int dy=0; dy<3; dy++){
      const float* cr = &ct[(row+dy)*128];
      float l  = (xx>0)    ? cr[xx-1] : 0.0f;
      float mm = cr[xx];
      float r  = cr[xx+1];
      float rr = (xx<126)  ? cr[xx+2] : 0.0f;
      c0 += l*w9[dy*3+0] + mm*w9[dy*3+1] + r*w9[dy*3+2];
      c1 += mm*w9[dy*3+0] + r*w9[dy*3+1] + rr*w9[dy*3+2];
    }
    size_t g = gbase + (size_t)(row*128 + xx);
    float2 xc = *(const float2*)&xcs[g];
    float2 o;
    o.x = z.x*0.015625f + xc.x + c0;
    o.y = z.y*0.015625f + xc.y + c1;
    *(float2*)&sbuf[g] = o;
  }
}

// ---- LN stats over channels ----
__global__ __launch_bounds__(256) void k_stats(const float* __restrict__ sbuf, float* __restrict__ stats){
  int g = blockIdx.x*256 + threadIdx.x;
  int b = g >> 14, hw = g & 16383;
  const float* p = sbuf + (size_t)b*C_*HW_ + hw;
  float s1 = 0.0f, s2 = 0.0f;
  for (int c=0; c<C_; c++){
    float v = p[(size_t)c*HW_];
    s1 += v; s2 += v*v;
  }
  float mean = s1 * (1.0f/256.0f);
  float var  = s2 * (1.0f/256.0f) - mean*mean;
  stats[g] = mean;
  stats[65536 + g] = 1.0f / sqrtf(var + 1e-5f);
}

// ---- LN apply + cond scale/shift, coalesced transpose to (B,HW,C) ----
__global__ __launch_bounds__(256) void k_apply(const float* __restrict__ sbuf, const float* __restrict__ stats,
                                               const float* __restrict__ timev,
                                               const float* __restrict__ nww, const float* __restrict__ nwb,
                                               const float* __restrict__ nbw, const float* __restrict__ nbb,
                                               float* __restrict__ out){
  __shared__ float tile[64][65];
  __shared__ float wv[64], bv[64], mv[64], rv[64];
  int b = blockIdx.z, c0 = blockIdx.y*64, hw0 = blockIdx.x*64;
  int tid = threadIdx.x;
  if (tid < 64){
    float t = timev[b];
    int c = c0 + tid;
    wv[tid] = t*nww[c] + nwb[c];
    bv[tid] = t*nbw[c] + nbb[c];
    mv[tid] = stats[(b<<14) + hw0 + tid];
    rv[tid] = stats[65536 + (b<<14) + hw0 + tid];
  }
  #pragma unroll
  for (int q=0;q<16;q++){
    int p = tid + q*256;
    int cl = p >> 6, hwl = p & 63;
    tile[cl][hwl] = sbuf[((size_t)(b*C_+c0+cl))*HW_ + hw0 + hwl];
  }
  __syncthreads();
  #pragma unroll
  for (int q=0;q<16;q++){
    int p = tid + q*256;
    int hwl = p >> 6, cl = p & 63;
    float v = tile[cl][hwl];
    out[((size_t)(b*HW_+hw0+hwl))*C_ + c0 + cl] = wv[cl]*((v - mv[hwl])*rv[hwl]) + bv[cl];
  }
}

extern "C" void kernel_launch(void* const* d_in, const int* in_sizes, int n_in,
                              void* d_out, int out_size, void* d_ws, size_t ws_size,
                              hipStream_t stream){
  const float* x      = (const float*)d_in[0];
  const float* timev  = (const float*)d_in[1];
  const float* w_real = (const float*)d_in[2];
  const float* w_imag = (const float*)d_in[3];
  const float* conv_w = (const float*)d_in[4];
  const float* lin_w  = (const float*)d_in[5];
  const float* lin_b  = (const float*)d_in[6];
  const float* mlp_w1 = (const float*)d_in[7];
  const float* mlp_b1 = (const float*)d_in[8];
  const float* mlp_w2 = (const float*)d_in[9];
  const float* mlp_b2 = (const float*)d_in[10];
  const float* norm_ww= (const float*)d_in[11];
  const float* norm_wb= (const float*)d_in[12];
  const float* norm_bw= (const float*)d_in[13];
  const float* norm_bb= (const float*)d_in[14];
  const float* kxp    = (const float*)d_in[15];
  const float* kyp    = (const float*)d_in[16];

  // workspace layout (floats) — total 51,093,600 floats = 194.9 MiB
  float* ws = (float*)d_ws;
  float*  alpha  = ws;                               // 6144
  unsigned char* bid = (unsigned char*)(ws + 6144);  // 8320 B (2080 floats)
  float*  counts = ws + 8224;                        // 64
  float*  stats  = ws + 8288;                        // 131072
  short*  Wre_bf = (short*)(ws + 139360);            // 65536 shorts (32768 floats)
  short*  Wim_bf = (short*)(ws + 172128);            // 65536 shorts
  short*  WL_bf  = (short*)(ws + 204896);            // 65536 shorts
  float*  x2     = ws + 237664;                      // 16,777,216 (live until inv_rows: conv input)
  float2* Xf     = (float2*)(ws + 17014880);         // 17,039,360 floats (Xf, then Y1 in-place)
  float*  CbF    = ws + 34054240;                    // 17,039,360 floats, multi-use:
  float2* X1     = (float2*)CbF;                     //   X1 (fwd FFT intermediate, dead after fwd_cols_gate)
  short*  XtRe   = (short*)CbF;                      //   then Xt bf16 planes [b][2880][256]
  short*  XtIm   = (short*)(CbF + 1474560);
  float2* mappedP= (float2*)(CbF + 2949120);         //   packed mapped [b][c][2880] (5,898,240 floats)
  float*  sb     = CbF;                              //   then final sum (16,777,216) after inv_cols
  float*  xcs    = (float*)d_out;                    // pointwise output, scratch in d_out
  float*  out    = (float*)d_out;

  k_transpose    <<<dim3(256, 4, B_), dim3(64,16), 0, stream>>>(x, x2);
  k_counts       <<<1, 256, 0, stream>>>(counts, bid);
  k_wbf16        <<<dim3(256, 3), 256, 0, stream>>>(w_real, w_imag, lin_w, Wre_bf, Wim_bf, WL_bf);
  k_fwd_rows     <<<4096, 256, 0, stream>>>(x2, X1);
  k_fwd_cols_gate<<<1024, 256, 0, stream>>>(X1, Xf, counts, bid, mlp_w1, mlp_b1, mlp_w2, mlp_b2, alpha);
  k_xt           <<<dim3(72, 2, B_), 256, 0, stream>>>(Xf, XtRe, XtIm);
  k_pw_mfma      <<<dim3(256, 4, B_), 256, 0, stream>>>(x, WL_bf, lin_b, xcs);
  k_mix_mfma     <<<dim3(45, 4, B_), 256, 0, stream>>>(Wre_bf, Wim_bf, XtRe, XtIm, kxp, kyp, mappedP);
  k_inv_cols     <<<dim3(5, 1024), 256, 0, stream>>>(Xf, mappedP, alpha, bid, kxp, kyp);
  k_inv_rows     <<<4096, 256, 0, stream>>>((const float2*)Xf, xcs, x2, conv_w, sb);
  k_stats        <<<256, 256, 0, stream>>>(sb, stats);
  k_apply        <<<dim3(256, 4, B_), 256, 0, stream>>>(sb, stats, timev, norm_ww, norm_wb, norm_bw, norm_bb, out);
}

// Round 2
// 483.473 us; speedup vs baseline: 1.1818x; 1.0322x over previous
//
#include <hip/hip_runtime.h>
#include <math.h>

#define B_ 4
#define C_ 256
#define RES_ 128
#define HW_ 16384
#define WF_ 65
#define F_ 8320
#define FP_ 2880   // packed masked-freq grid: 72 rows x 40 cols (covers runtime 71x36)

typedef __attribute__((ext_vector_type(8))) short bf16x8;
typedef __attribute__((ext_vector_type(16))) float f32x16;

__device__ __forceinline__ int brev7(int j){ return (int)(__brev((unsigned)j) >> 25); }
__device__ __forceinline__ int brev6(int j){ return (int)(__brev((unsigned)j) >> 26); }

__device__ __forceinline__ short f2bf(float f){
  unsigned u = __float_as_uint(f);
  unsigned r = (u + 0x7FFFu + ((u>>16)&1u)) >> 16;
  return (short)r;
}

__device__ __forceinline__ bf16x8 lds_frag(const short* p){
  union { bf16x8 v; int2 d[2]; } u;
  u.d[0] = *(const int2*)p;
  u.d[1] = *(const int2*)(p+4);
  return u.v;
}
__device__ __forceinline__ void lds_store8(short* p, bf16x8 v){
  union { bf16x8 v; int2 d[2]; } u; u.v = v;
  *(int2*)p = u.d[0]; *(int2*)(p+4) = u.d[1];
}

// ---- band id, bit-exact vs numpy float32 ----
__device__ __forceinline__ int band_of(int row, int col){
  float yy = __fdiv_rn((float)row, 127.0f);
  float xx = __fdiv_rn((float)col, 64.0f);
  float rr = __fsqrt_rn(__fadd_rn(__fmul_rn(yy,yy), __fmul_rn(xx,xx)));
  float rm = __fadd_rn(__fsqrt_rn(2.0f), 1e-8f);
  float rn = __fdiv_rn(rr, rm);
  int b = (int)floorf(__fmul_rn(rn, 6.0f));
  return b > 5 ? 5 : b;
}

__device__ __forceinline__ float sigmoidf_(float v){ return 1.0f/(1.0f+expf(-v)); }

// ---- in-LDS radix-2 DIF FFT, length 128 (cols kernels) ----
template<int SGN, int NROWS>
__device__ __forceinline__ void fft128_lds(float2* buf, int rstride, int tid, const float2* tw){
  const int total = NROWS*64;
  #pragma unroll
  for (int stage=0; stage<7; stage++){
    int half = 64 >> stage;
    __syncthreads();
    for (int idx = tid; idx < total; idx += 256){
      int row = idx % NROWS;
      int t   = idx / NROWS;
      int j   = t & (half-1);
      int i0  = ((t >> (6-stage)) << (7-stage)) + j;
      int i1  = i0 + half;
      float2* rb = buf + row*rstride;
      float2 a = rb[i0], b = rb[i1];
      float2 w = tw[j << stage];
      float dx = a.x - b.x, dy = a.y - b.y;
      rb[i0] = make_float2(a.x+b.x, a.y+b.y);
      float ws = (SGN < 0) ? -w.y : w.y;
      rb[i1] = make_float2(dx*w.x - dy*ws, dx*ws + dy*w.x);
    }
  }
  __syncthreads();
}

// ---- wave-synchronous 64-pt radix-2 DIF FFT, one complex value per lane ----
// stw[s] = e^{+2*pi*i*((lane & (H-1)) << s)/64}, H = 32>>s. Output bit-reversed across lanes.
template<int SGN>
__device__ __forceinline__ float2 wave_fft64(float2 v, const float2* stw, int lane){
  #pragma unroll
  for (int s=0; s<6; s++){
    int H = 32 >> s;
    float ox = __shfl_xor(v.x, H);
    float oy = __shfl_xor(v.y, H);
    bool hi = (lane & H) != 0;
    float2 w = stw[s];
    float ws = (SGN < 0) ? -w.y : w.y;
    float sx = v.x + ox, sy = v.y + oy;
    float dx = ox - v.x, dy = oy - v.y;   // (a - b) on the hi lane
    float rx = dx*w.x - dy*ws;
    float ry = dx*ws + dy*w.x;
    v.x = hi ? rx : sx;
    v.y = hi ? ry : sy;
  }
  return v;
}

// per-lane stage twiddles: identical float values to the old 128-entry table lookups
__device__ __forceinline__ void make_stage_tw(float2* stw, int lane){
  #pragma unroll
  for (int s=0; s<6; s++){
    int H = 32 >> s;
    int t = (lane & (H-1)) << s;
    float sn, cs;
    sincosf(6.283185307179586f*(float)t/64.0f, &sn, &cs);
    stw[s] = make_float2(cs, sn);
  }
}

// ---- (B,HW,C) -> (B,C,HW) transpose ----
__global__ __launch_bounds__(1024) void k_transpose(const float* __restrict__ x, float* __restrict__ x2){
  __shared__ float tile[64][65];
  int b = blockIdx.z;
  int hw0 = blockIdx.x*64, c0 = blockIdx.y*64;
  int tx = threadIdx.x, ty = threadIdx.y;
  #pragma unroll
  for (int i=0;i<4;i++){
    int hw = hw0 + ty + i*16;
    tile[ty+i*16][tx] = x[((size_t)b*HW_ + hw)*C_ + c0 + tx];
  }
  __syncthreads();
  #pragma unroll
  for (int i=0;i<4;i++){
    int c = c0 + ty + i*16;
    x2[((size_t)b*C_ + c)*HW_ + hw0 + tx] = tile[tx][ty+i*16];
  }
}

// ---- counts + band-id table ----
__global__ __launch_bounds__(256) void k_counts(float* __restrict__ counts, unsigned char* __restrict__ bid){
  int tid = threadIdx.x;
  float acc[6] = {0,0,0,0,0,0};
  for (int f = tid; f < F_; f += 256){
    int row = f / WF_, col = f - row*WF_;
    int bnd = band_of(row, col);
    bid[f] = (unsigned char)bnd;
    #pragma unroll
    for (int n=0;n<6;n++) acc[n] += (bnd==n) ? 1.0f : 0.0f;
  }
  __shared__ float red[6][256];
  #pragma unroll
  for (int n=0;n<6;n++) red[n][tid] = acc[n];
  __syncthreads();
  for (int s=128; s>0; s>>=1){
    if (tid < s){
      #pragma unroll
      for (int n=0;n<6;n++) red[n][tid] += red[n][tid+s];
    }
    __syncthreads();
  }
  if (tid < 6) counts[tid] = fmaxf(red[tid][0], 1.0f);
}

// ---- convert W matrices to bf16 planes ----
__global__ __launch_bounds__(256) void k_wbf16(const float* __restrict__ wre, const float* __restrict__ wim,
                                               const float* __restrict__ lw,
                                               short* __restrict__ Wre, short* __restrict__ Wim,
                                               short* __restrict__ WL){
  int c = blockIdx.x, tid = threadIdx.x, plane = blockIdx.y;
  int idx = c*C_ + tid;
  if (plane == 0)      Wre[idx] = f2bf(wre[idx]);
  else if (plane == 1) Wim[idx] = f2bf(wim[idx]);
  else                 WL[idx]  = f2bf(lw[idx]);
}

// ---- forward row rFFT via wave-shuffle 64-pt FFT: x2 -> X1 (unnormalized 128-pt r2c) ----
// no LDS, no barriers: each wave owns its rows end-to-end.
__global__ __launch_bounds__(256) void k_fwd_rows(const float* __restrict__ x2, float2* __restrict__ X1){
  int tid = threadIdx.x;
  int lane = tid & 63, wv = tid >> 6;
  float2 stw[6];
  make_stage_tw(stw, lane);
  float sn128, cs128;
  sincosf(6.283185307179586f*(float)lane/128.0f, &sn128, &cs128);
  int slice = blockIdx.x >> 2;
  int r0 = (blockIdx.x & 3) * 32;
  const float* img = x2 + (size_t)slice*HW_ + (size_t)r0*128;
  float2* dst = X1 + (size_t)slice*F_ + (size_t)r0*WF_;
  #pragma unroll
  for (int i=0; i<8; i++){
    int row = wv*8 + i;
    // y[m] = x[2m] + i x[2m+1]
    float2 y = *(const float2*)(img + row*128 + lane*2);
    float2 v = wave_fft64<-1>(y, stw, lane);
    // un-bit-reverse: Yk = Y[lane], Ym = Y[(64-lane)&63]
    int rbk = brev6(lane);
    float2 Yk; Yk.x = __shfl(v.x, rbk); Yk.y = __shfl(v.y, rbk);
    int rbm = brev6((64 - lane) & 63);
    float2 Ym; Ym.x = __shfl(v.x, rbm); Ym.y = __shfl(v.y, rbm);
    // X[k] = 0.5*(s - i*e^{-i th}*d), th = 2 pi k/128
    float sx = Yk.x + Ym.x, sy = Yk.y - Ym.y;
    float dx = Yk.x - Ym.x, dy = Yk.y + Ym.y;
    dst[row*WF_ + lane] = make_float2(0.5f*(sx - sn128*dx + cs128*dy),
                                      0.5f*(sy - cs128*dx - sn128*dy));
    if (lane == 0)
      dst[row*WF_ + 64] = make_float2(Yk.x - Yk.y, 0.0f);   // X[64] = sum_even - sum_odd
  }
}

// ---- forward col FFT + ortho scale + band-gate ----
__global__ __launch_bounds__(256) void k_fwd_cols_gate(const float2* __restrict__ X1, float2* __restrict__ Xf,
                                                       const float* __restrict__ counts, const unsigned char* __restrict__ bid,
                                                       const float* __restrict__ w1, const float* __restrict__ b1,
                                                       const float* __restrict__ w2, const float* __restrict__ b2,
                                                       float* __restrict__ alpha){
  __shared__ float2 cbuf[13*129];
  __shared__ float2 tw[64];
  __shared__ float red[6][256];
  __shared__ float means[6], h[128];
  int tid = threadIdx.x;
  if (tid < 64){ float s,c; sincosf(6.283185307179586f*(float)tid/128.0f,&s,&c); tw[tid]=make_float2(c,s); }
  int slice = blockIdx.x;
  const float2* xin = X1 + (size_t)slice*F_;
  float2* xout = Xf + (size_t)slice*F_;
  float acc[6] = {0,0,0,0,0,0};
  for (int chunk=0; chunk<5; chunk++){
    int c0 = chunk*13;
    __syncthreads();
    for (int p = tid; p < 13*128; p += 256){
      int y = p / 13, col = p - y*13;
      cbuf[col*129 + y] = xin[y*WF_ + c0 + col];
    }
    fft128_lds<-1,13>(cbuf, 129, tid, tw);
    for (int p = tid; p < 13*128; p += 256){
      int ky = p / 13, col = p - ky*13, kx = c0 + col;
      float2 v = cbuf[col*129 + brev7(ky)];
      v.x *= 0.0078125f; v.y *= 0.0078125f;
      int f = ky*WF_ + kx;
      xout[f] = v;
      float m = __fsqrt_rn(v.x*v.x + v.y*v.y);
      int bb = (int)bid[f];
      #pragma unroll
      for (int n=0;n<6;n++) acc[n] += (bb==n) ? m : 0.0f;
    }
  }
  __syncthreads();
  #pragma unroll
  for (int n=0;n<6;n++) red[n][tid] = acc[n];
  __syncthreads();
  for (int s=128; s>0; s>>=1){
    if (tid < s){
      #pragma unroll
      for (int n=0;n<6;n++) red[n][tid] += red[n][tid+s];
    }
    __syncthreads();
  }
  if (tid < 6) means[tid] = red[tid][0] / (counts[tid] + 1e-6f);
  __syncthreads();
  if (tid < 128){
    float hv = b1[tid];
    #pragma unroll
    for (int n=0;n<6;n++) hv += means[n]*w1[tid*6+n];
    h[tid] = fmaxf(hv, 0.0f);
  }
  __syncthreads();
  if (tid < 6){
    float o = b2[tid];
    for (int j=0;j<128;j++) o += h[j]*w2[tid*128+j];
    alpha[slice*6 + tid] = sigmoidf_(o);
  }
}

// ---- pack+transpose Xf (static 72x40 region) -> Xt planes [b][fp][d] bf16 ----
__global__ __launch_bounds__(256) void k_xt(const float2* __restrict__ Xf,
                                            short* __restrict__ XtRe, short* __restrict__ XtIm){
  __shared__ float2 tile[40][129];
  int tid = threadIdx.x;
  int ky = blockIdx.x, d0 = blockIdx.y*128, b = blockIdx.z;
  const float2* xb = Xf + ((size_t)(b*C_ + d0))*F_ + ky*WF_;
  #pragma unroll
  for (int i=0;i<20;i++){
    int p = tid + i*256;
    int d = p / 40, kx = p - d*40;
    tile[kx][d] = xb[(size_t)d*F_ + kx];
  }
  __syncthreads();
  #pragma unroll
  for (int i=0;i<20;i++){
    int p = tid + i*256;
    int kx = p >> 7, d = p & 127;
    float2 v = tile[kx][d];
    size_t o = ((size_t)b*FP_ + ky*40 + kx)*C_ + d0 + d;
    XtRe[o] = f2bf(v.x);
    XtIm[o] = f2bf(v.y);
  }
}

// ---- MFMA complex channel mix: mappedP[c][fp] = sum_d W[c][d] * X[fp][d] ----
__global__ __launch_bounds__(256) void k_mix_mfma(const short* __restrict__ Wre, const short* __restrict__ Wim,
                                                  const short* __restrict__ XtRe, const short* __restrict__ XtIm,
                                                  const float* __restrict__ kxp, const float* __restrict__ kyp,
                                                  float2* __restrict__ mappedP){
  __shared__ short Are[64][36], Aim[64][36], Bre[64][36], Bim[64][36];
  int tid = threadIdx.x;
  int fp0 = blockIdx.x*64, c0 = blockIdx.y*64, b = blockIdx.z;
  int lane = tid & 63, w = tid >> 6;
  int mt = (w >> 1)*32, nt = (w & 1)*32;
  f32x16 accre = {0.f,0.f,0.f,0.f,0.f,0.f,0.f,0.f,0.f,0.f,0.f,0.f,0.f,0.f,0.f,0.f};
  f32x16 accim = {0.f,0.f,0.f,0.f,0.f,0.f,0.f,0.f,0.f,0.f,0.f,0.f,0.f,0.f,0.f,0.f};
  const short* xrb = XtRe + ((size_t)b*FP_ + fp0)*C_;
  const short* xib = XtIm + ((size_t)b*FP_ + fp0)*C_;
  int row4 = tid >> 2, part = tid & 3;
  for (int kc=0; kc<8; kc++){
    int d0 = kc*32;
    __syncthreads();
    lds_store8(&Are[row4][part*8], *(const bf16x8*)&Wre[(c0+row4)*C_ + d0 + part*8]);
    lds_store8(&Aim[row4][part*8], *(const bf16x8*)&Wim[(c0+row4)*C_ + d0 + part*8]);
    lds_store8(&Bre[row4][part*8], *(const bf16x8*)&xrb[(size_t)row4*C_ + d0 + part*8]);
    lds_store8(&Bim[row4][part*8], *(const bf16x8*)&xib[(size_t)row4*C_ + d0 + part*8]);
    __syncthreads();
    #pragma unroll
    for (int ks=0; ks<2; ks++){
      int koff = ks*16 + (lane>>5)*8;
      bf16x8 are = lds_frag(&Are[mt + (lane&31)][koff]);
      bf16x8 aim = lds_frag(&Aim[mt + (lane&31)][koff]);
      bf16x8 bre = lds_frag(&Bre[nt + (lane&31)][koff]);
      bf16x8 bim = lds_frag(&Bim[nt + (lane&31)][koff]);
      bf16x8 naim;
      { union { bf16x8 v; unsigned u[4]; } t1, t2; t1.v = aim;
        #pragma unroll
        for (int j=0;j<4;j++) t2.u[j] = t1.u[j] ^ 0x80008000u;
        naim = t2.v; }
      accre = __builtin_amdgcn_mfma_f32_32x32x16_bf16(are,  bre, accre, 0,0,0);
      accre = __builtin_amdgcn_mfma_f32_32x32x16_bf16(naim, bim, accre, 0,0,0);
      accim = __builtin_amdgcn_mfma_f32_32x32x16_bf16(are,  bim, accim, 0,0,0);
      accim = __builtin_amdgcn_mfma_f32_32x32x16_bf16(aim,  bre, accim, 0,0,0);
    }
  }
  float rowlim = floorf(sigmoidf_(kxp[0])*128.0f);
  float collim = floorf(sigmoidf_(kyp[0])*65.0f);
  int n = fp0 + nt + (lane & 31);
  int ky = n / 40, kx = n - ky*40;
  bool live = ((float)ky < rowlim) && ((float)kx < collim);
  #pragma unroll
  for (int reg=0; reg<16; reg++){
    int r = (reg & 3) + 8*(reg >> 2) + 4*(lane >> 5);
    int c = c0 + mt + r;
    if (live)
      mappedP[((size_t)(b*C_ + c))*FP_ + n] = make_float2(accre[reg], accim[reg]);
  }
}

// ---- MFMA pointwise: xcs[c][hw] = sum_d lin_w[c][d] * x[hw][d] + lin_b[c] ----
__global__ __launch_bounds__(256) void k_pw_mfma(const float* __restrict__ x, const short* __restrict__ WL,
                                                  const float* __restrict__ lb, float* __restrict__ xcs){
  __shared__ short As[64][36], Bs[64][36];
  int tid = threadIdx.x;
  int hw0 = blockIdx.x*64, c0 = blockIdx.y*64, b = blockIdx.z;
  int lane = tid & 63, w = tid >> 6;
  int mt = (w >> 1)*32, nt = (w & 1)*32;
  f32x16 acc = {0.f,0.f,0.f,0.f,0.f,0.f,0.f,0.f,0.f,0.f,0.f,0.f,0.f,0.f,0.f,0.f};
  const float* xb = x + ((size_t)b*HW_ + hw0)*C_;
  int row4 = tid >> 2, part = tid & 3;
  for (int kc=0; kc<8; kc++){
    int d0 = kc*32;
    __syncthreads();
    lds_store8(&As[row4][part*8], *(const bf16x8*)&WL[(c0+row4)*C_ + d0 + part*8]);
    {
      const float* src = &xb[(size_t)row4*C_ + d0 + part*8];
      float4 va = *(const float4*)src;
      float4 vb = *(const float4*)(src+4);
      bf16x8 bv;
      bv[0]=f2bf(va.x); bv[1]=f2bf(va.y); bv[2]=f2bf(va.z); bv[3]=f2bf(va.w);
      bv[4]=f2bf(vb.x); bv[5]=f2bf(vb.y); bv[6]=f2bf(vb.z); bv[7]=f2bf(vb.w);
      lds_store8(&Bs[row4][part*8], bv);
    }
    __syncthreads();
    #pragma unroll
    for (int ks=0; ks<2; ks++){
      int koff = ks*16 + (lane>>5)*8;
      bf16x8 a  = lds_frag(&As[mt + (lane&31)][koff]);
      bf16x8 bb = lds_frag(&Bs[nt + (lane&31)][koff]);
      acc = __builtin_amdgcn_mfma_f32_32x32x16_bf16(a, bb, acc, 0,0,0);
    }
  }
  int n = hw0 + nt + (lane & 31);
  #pragma unroll
  for (int reg=0; reg<16; reg++){
    int r = (reg & 3) + 8*(reg >> 2) + 4*(lane >> 5);
    int c = c0 + mt + r;
    xcs[((size_t)(b*C_ + c))*HW_ + n] = acc[reg] + lb[c];
  }
}

// ---- inverse col FFT with fused alpha-blend; Y1 written in place into Xf region ----
__global__ __launch_bounds__(256) void k_inv_cols(float2* __restrict__ XfY, const float2* __restrict__ mappedP,
                                                  const float* __restrict__ alpha, const unsigned char* __restrict__ bid,
                                                  const float* __restrict__ kxp, const float* __restrict__ kyp){
  __shared__ float2 cbuf[13*129];
  __shared__ float2 tw[64];
  __shared__ float al[6];
  int tid = threadIdx.x;
  int chunk = blockIdx.x, slice = blockIdx.y;
  int c0 = chunk*13;
  if (tid < 64){ float s,c; sincosf(6.283185307179586f*(float)tid/128.0f,&s,&c); tw[tid]=make_float2(c,s); }
  if (tid < 6) al[tid] = alpha[slice*6 + tid];
  float rowlim = floorf(sigmoidf_(kxp[0])*128.0f);
  float collim = floorf(sigmoidf_(kyp[0])*65.0f);
  __syncthreads();
  float2* xfb = XfY + (size_t)slice*F_;
  const float2* mpb = mappedP + (size_t)slice*FP_;
  for (int p = tid; p < 13*128; p += 256){
    int ky = p / 13, col = p - ky*13, kx = c0 + col;
    int f = ky*WF_ + kx;
    float a = al[(int)bid[f]];
    bool inm = ((float)ky < rowlim) && ((float)kx < collim);
    float2 v;
    if (inm){ v = mpb[ky*40 + kx]; v.x *= a; v.y *= a; }
    else    { v = xfb[f]; float om = 1.0f - a; v.x *= om; v.y *= om; }
    cbuf[col*129 + ky] = v;
  }
  fft128_lds<1,13>(cbuf, 129, tid, tw);
  for (int p = tid; p < 13*128; p += 256){
    int y = p / 13, col = p - y*13;
    xfb[y*WF_ + c0 + col] = cbuf[col*129 + brev7(y)];
  }
}

// ---- inverse row c2r via wave-shuffle 64-pt FFT + fused depthwise 3x3 conv + xcs -> sbuf ----
// only LDS left: the conv halo tile (one barrier).
__global__ __launch_bounds__(256) void k_inv_rows(const float2* __restrict__ Y1, const float* __restrict__ xcs,
                                                  const float* __restrict__ x2, const float* __restrict__ cw,
                                                  float* __restrict__ sbuf){
  __shared__ float ct[34*128];
  int tid = threadIdx.x;
  int lane = tid & 63, wv = tid >> 6;
  float2 stw[6];
  make_stage_tw(stw, lane);
  float sn128, cs128;
  sincosf(6.283185307179586f*(float)lane/128.0f, &sn128, &cs128);
  int slice = blockIdx.x >> 2;
  int ch = slice & 255;
  int r0 = (blockIdx.x & 3) * 32;
  const float* img = x2 + (size_t)slice*HW_;
  #pragma unroll
  for (int q=0;q<17;q++){
    int p = tid + q*256;
    int row = p >> 7, xx = p & 127;
    int sr = r0 - 1 + row;
    ct[p] = ((unsigned)sr < 128u) ? img[sr*128+xx] : 0.0f;
  }
  float w9[9];
  #pragma unroll
  for (int k=0;k<9;k++) w9[k] = cw[ch*9+k];
  __syncthreads();
  const float2* src = Y1 + (size_t)slice*F_ + (size_t)r0*WF_;
  size_t gbase = (size_t)slice*HW_ + (size_t)r0*128;
  #pragma unroll
  for (int i=0;i<8;i++){
    int row = wv*8 + i;
    const float2* rs = src + row*WF_;
    // Y[k] = 0.5*(X[k]+conj(X[64-k])) + 0.5*i*e^{+i th_k}*(X[k]-conj(X[64-k])), th_k = 2 pi k/128
    float2 a = rs[lane];
    float2 b = rs[64 - lane];
    if (lane == 0){ a.y = 0.0f; b.y = 0.0f; }   // force Im(X[0]) = Im(X[64]) = 0
    float sx = a.x + b.x, sy = a.y - b.y;
    float dx = a.x - b.x, dy = a.y + b.y;
    float2 yk = make_float2(0.5f*(sx - sn128*dx - cs128*dy),
                            0.5f*(sy + cs128*dx - sn128*dy));
    float2 v = wave_fft64<1>(yk, stw, lane);
    // un-bit-reverse: lane m holds z[m]; x[2m] = Re/64, x[2m+1] = Im/64
    int rbk = brev6(lane);
    float2 z; z.x = __shfl(v.x, rbk); z.y = __shfl(v.y, rbk);
    int xx = lane << 1;
    float c0 = 0.0f, c1 = 0.0f;
    #pragma unroll
    for (int dy2=0; dy2<3; dy2++){
      const float* cr = &ct[(row+dy2)*128];
      float l  = (xx>0)    ? cr[xx-1] : 0.0f;
      float mm = cr[xx];
      float r  = cr[xx+1];
      float rr = (xx<126)  ? cr[xx+2] : 0.0f;
      c0 += l*w9[dy2*3+0] + mm*w9[dy2*3+1] + r*w9[dy2*3+2];
      c1 += mm*w9[dy2*3+0] + r*w9[dy2*3+1] + rr*w9[dy2*3+2];
    }
    size_t g = gbase + (size_t)(row*128 + xx);
    float2 xc = *(const float2*)&xcs[g];
    float2 o;
    o.x = z.x*0.015625f + xc.x + c0;
    o.y = z.y*0.015625f + xc.y + c1;
    *(float2*)&sbuf[g] = o;
  }
}

// ---- LN stats over channels ----
__global__ __launch_bounds__(256) void k_stats(const float* __restrict__ sbuf, float* __restrict__ stats){
  int g = blockIdx.x*256 + threadIdx.x;
  int b = g >> 14, hw = g & 16383;
  const float* p = sbuf + (size_t)b*C_*HW_ + hw;
  float s1 = 0.0f, s2 = 0.0f;
  for (int c=0; c<C_; c++){
    float v = p[(size_t)c*HW_];
    s1 += v; s2 += v*v;
  }
  float mean = s1 * (1.0f/256.0f);
  float var  = s2 * (1.0f/256.0f) - mean*mean;
  stats[g] = mean;
  stats[65536 + g] = 1.0f / sqrtf(var + 1e-5f);
}

// ---- LN apply + cond scale/shift, coalesced transpose to (B,HW,C) ----
__global__ __launch_bounds__(256) void k_apply(const float* __restrict__ sbuf, const float* __restrict__ stats,
                                               const float* __restrict__ timev,
                                               const float* __restrict__ nww, const float* __restrict__ nwb,
                                               const float* __restrict__ nbw, const float* __restrict__ nbb,
                                               float* __restrict__ out){
  __shared__ float tile[64][65];
  __shared__ float wv[64], bv[64], mv[64], rv[64];
  int b = blockIdx.z, c0 = blockIdx.y*64, hw0 = blockIdx.x*64;
  int tid = threadIdx.x;
  if (tid < 64){
    float t = timev[b];
    int c = c0 + tid;
    wv[tid] = t*nww[c] + nwb[c];
    bv[tid] = t*nbw[c] + nbb[c];
    mv[tid] = stats[(b<<14) + hw0 + tid];
    rv[tid] = stats[65536 + (b<<14) + hw0 + tid];
  }
  #pragma unroll
  for (int q=0;q<16;q++){
    int p = tid + q*256;
    int cl = p >> 6, hwl = p & 63;
    tile[cl][hwl] = sbuf[((size_t)(b*C_+c0+cl))*HW_ + hw0 + hwl];
  }
  __syncthreads();
  #pragma unroll
  for (int q=0;q<16;q++){
    int p = tid + q*256;
    int hwl = p >> 6, cl = p & 63;
    float v = tile[cl][hwl];
    out[((size_t)(b*HW_+hw0+hwl))*C_ + c0 + cl] = wv[cl]*((v - mv[hwl])*rv[hwl]) + bv[cl];
  }
}

extern "C" void kernel_launch(void* const* d_in, const int* in_sizes, int n_in,
                              void* d_out, int out_size, void* d_ws, size_t ws_size,
                              hipStream_t stream){
  const float* x      = (const float*)d_in[0];
  const float* timev  = (const float*)d_in[1];
  const float* w_real = (const float*)d_in[2];
  const float* w_imag = (const float*)d_in[3];
  const float* conv_w = (const float*)d_in[4];
  const float* lin_w  = (const float*)d_in[5];
  const float* lin_b  = (const float*)d_in[6];
  const float* mlp_w1 = (const float*)d_in[7];
  const float* mlp_b1 = (const float*)d_in[8];
  const float* mlp_w2 = (const float*)d_in[9];
  const float* mlp_b2 = (const float*)d_in[10];
  const float* norm_ww= (const float*)d_in[11];
  const float* norm_wb= (const float*)d_in[12];
  const float* norm_bw= (const float*)d_in[13];
  const float* norm_bb= (const float*)d_in[14];
  const float* kxp    = (const float*)d_in[15];
  const float* kyp    = (const float*)d_in[16];

  // workspace layout (floats) — total 51,093,600 floats = 194.9 MiB
  float* ws = (float*)d_ws;
  float*  alpha  = ws;                               // 6144
  unsigned char* bid = (unsigned char*)(ws + 6144);  // 8320 B (2080 floats)
  float*  counts = ws + 8224;                        // 64
  float*  stats  = ws + 8288;                        // 131072
  short*  Wre_bf = (short*)(ws + 139360);            // 65536 shorts (32768 floats)
  short*  Wim_bf = (short*)(ws + 172128);            // 65536 shorts
  short*  WL_bf  = (short*)(ws + 204896);            // 65536 shorts
  float*  x2     = ws + 237664;                      // 16,777,216 (live until inv_rows: conv input)
  float2* Xf     = (float2*)(ws + 17014880);         // 17,039,360 floats (Xf, then Y1 in-place)
  float*  CbF    = ws + 34054240;                    // 17,039,360 floats, multi-use:
  float2* X1     = (float2*)CbF;                     //   X1 (fwd FFT intermediate, dead after fwd_cols_gate)
  short*  XtRe   = (short*)CbF;                      //   then Xt bf16 planes [b][2880][256]
  short*  XtIm   = (short*)(CbF + 1474560);
  float2* mappedP= (float2*)(CbF + 2949120);         //   packed mapped [b][c][2880] (5,898,240 floats)
  float*  sb     = CbF;                              //   then final sum (16,777,216) after inv_cols
  float*  xcs    = (float*)d_out;                    // pointwise output, scratch in d_out
  float*  out    = (float*)d_out;

  k_transpose    <<<dim3(256, 4, B_), dim3(64,16), 0, stream>>>(x, x2);
  k_counts       <<<1, 256, 0, stream>>>(counts, bid);
  k_wbf16        <<<dim3(256, 3), 256, 0, stream>>>(w_real, w_imag, lin_w, Wre_bf, Wim_bf, WL_bf);
  k_fwd_rows     <<<4096, 256, 0, stream>>>(x2, X1);
  k_fwd_cols_gate<<<1024, 256, 0, stream>>>(X1, Xf, counts, bid, mlp_w1, mlp_b1, mlp_w2, mlp_b2, alpha);
  k_xt           <<<dim3(72, 2, B_), 256, 0, stream>>>(Xf, XtRe, XtIm);
  k_pw_mfma      <<<dim3(256, 4, B_), 256, 0, stream>>>(x, WL_bf, lin_b, xcs);
  k_mix_mfma     <<<dim3(45, 4, B_), 256, 0, stream>>>(Wre_bf, Wim_bf, XtRe, XtIm, kxp, kyp, mappedP);
  k_inv_cols     <<<dim3(5, 1024), 256, 0, stream>>>(Xf, mappedP, alpha, bid, kxp, kyp);
  k_inv_rows     <<<4096, 256, 0, stream>>>((const float2*)Xf, xcs, x2, conv_w, sb);
  k_stats        <<<256, 256, 0, stream>>>(sb, stats);
  k_apply        <<<dim3(256, 4, B_), 256, 0, stream>>>(sb, stats, timev, norm_ww, norm_wb, norm_bw, norm_bb, out);
}

// Round 3
// 450.743 us; speedup vs baseline: 1.2676x; 1.0726x over previous
//
#include <hip/hip_runtime.h>
#include <math.h>

#define B_ 4
#define C_ 256
#define RES_ 128
#define HW_ 16384
#define WF_ 65
#define F_ 8320
#define FP_ 2880   // packed masked-freq grid: 40 cols x 72 rows, fp = kx*72 + ky (covers runtime 36x71)

typedef __attribute__((ext_vector_type(8))) short bf16x8;
typedef __attribute__((ext_vector_type(16))) float f32x16;

__device__ __forceinline__ int brev6(int j){ return (int)(__brev((unsigned)j) >> 26); }

__device__ __forceinline__ short f2bf(float f){
  unsigned u = __float_as_uint(f);
  unsigned r = (u + 0x7FFFu + ((u>>16)&1u)) >> 16;
  return (short)r;
}

__device__ __forceinline__ bf16x8 lds_frag(const short* p){
  union { bf16x8 v; int2 d[2]; } u;
  u.d[0] = *(const int2*)p;
  u.d[1] = *(const int2*)(p+4);
  return u.v;
}
__device__ __forceinline__ void lds_store8(short* p, bf16x8 v){
  union { bf16x8 v; int2 d[2]; } u; u.v = v;
  *(int2*)p = u.d[0]; *(int2*)(p+4) = u.d[1];
}

// ---- band id, bit-exact vs numpy float32 ----
__device__ __forceinline__ int band_of(int row, int col){
  float yy = __fdiv_rn((float)row, 127.0f);
  float xx = __fdiv_rn((float)col, 64.0f);
  float rr = __fsqrt_rn(__fadd_rn(__fmul_rn(yy,yy), __fmul_rn(xx,xx)));
  float rm = __fadd_rn(__fsqrt_rn(2.0f), 1e-8f);
  float rn = __fdiv_rn(rr, rm);
  int b = (int)floorf(__fmul_rn(rn, 6.0f));
  return b > 5 ? 5 : b;
}

__device__ __forceinline__ float sigmoidf_(float v){ return 1.0f/(1.0f+expf(-v)); }

// ---- wave-synchronous 64-pt radix-2 DIF FFT, one complex value per lane ----
// Output bit-reversed across lanes: result for index r lives at lane brev6(r).
template<int SGN>
__device__ __forceinline__ float2 wave_fft64(float2 v, const float2* stw, int lane){
  #pragma unroll
  for (int s=0; s<6; s++){
    int H = 32 >> s;
    float ox = __shfl_xor(v.x, H);
    float oy = __shfl_xor(v.y, H);
    bool hi = (lane & H) != 0;
    float2 w = stw[s];
    float ws = (SGN < 0) ? -w.y : w.y;
    float sx = v.x + ox, sy = v.y + oy;
    float dx = ox - v.x, dy = oy - v.y;   // (a - b) on the hi lane
    float rx = dx*w.x - dy*ws;
    float ry = dx*ws + dy*w.x;
    v.x = hi ? rx : sx;
    v.y = hi ? ry : sy;
  }
  return v;
}

// per-lane stage twiddles: identical float values to a 128-entry table at even indices
__device__ __forceinline__ void make_stage_tw(float2* stw, int lane){
  #pragma unroll
  for (int s=0; s<6; s++){
    int H = 32 >> s;
    int t = (lane & (H-1)) << s;
    float sn, cs;
    sincosf(6.283185307179586f*(float)t/64.0f, &sn, &cs);
    stw[s] = make_float2(cs, sn);
  }
}

// redistribute (val[2l], val[2l+1]) per lane -> u0 = val[l], u1 = val[l+64]
__device__ __forceinline__ void redist2(float2 a0, float2 a1, int lane, float2& u0, float2& u1){
  int s0 = lane >> 1, s1 = s0 + 32;
  bool odd = (lane & 1) != 0;
  float t0x = __shfl(a0.x, s0), t0y = __shfl(a0.y, s0);
  float t1x = __shfl(a1.x, s0), t1y = __shfl(a1.y, s0);
  u0 = odd ? make_float2(t1x, t1y) : make_float2(t0x, t0y);
  float q0x = __shfl(a0.x, s1), q0y = __shfl(a0.y, s1);
  float q1x = __shfl(a1.x, s1), q1y = __shfl(a1.y, s1);
  u1 = odd ? make_float2(q1x, q1y) : make_float2(q0x, q0y);
}

// ---- (B,HW,C) -> (B,C,HW) transpose ----
__global__ __launch_bounds__(1024) void k_transpose(const float* __restrict__ x, float* __restrict__ x2){
  __shared__ float tile[64][65];
  int b = blockIdx.z;
  int hw0 = blockIdx.x*64, c0 = blockIdx.y*64;
  int tx = threadIdx.x, ty = threadIdx.y;
  #pragma unroll
  for (int i=0;i<4;i++){
    int hw = hw0 + ty + i*16;
    tile[ty+i*16][tx] = x[((size_t)b*HW_ + hw)*C_ + c0 + tx];
  }
  __syncthreads();
  #pragma unroll
  for (int i=0;i<4;i++){
    int c = c0 + ty + i*16;
    x2[((size_t)b*C_ + c)*HW_ + hw0 + tx] = tile[tx][ty+i*16];
  }
}

// ---- counts + transposed band-id table: bid_t[kx*128 + ky] ----
__global__ __launch_bounds__(256) void k_counts(float* __restrict__ counts, unsigned char* __restrict__ bid_t){
  int tid = threadIdx.x;
  float acc[6] = {0,0,0,0,0,0};
  for (int p = tid; p < F_; p += 256){
    int kx = p >> 7, ky = p & 127;
    int bnd = band_of(ky, kx);
    bid_t[p] = (unsigned char)bnd;
    #pragma unroll
    for (int n=0;n<6;n++) acc[n] += (bnd==n) ? 1.0f : 0.0f;
  }
  __shared__ float red[6][256];
  #pragma unroll
  for (int n=0;n<6;n++) red[n][tid] = acc[n];
  __syncthreads();
  for (int s=128; s>0; s>>=1){
    if (tid < s){
      #pragma unroll
      for (int n=0;n<6;n++) red[n][tid] += red[n][tid+s];
    }
    __syncthreads();
  }
  if (tid < 6) counts[tid] = fmaxf(red[tid][0], 1.0f);
}

// ---- convert W matrices to bf16 planes ----
__global__ __launch_bounds__(256) void k_wbf16(const float* __restrict__ wre, const float* __restrict__ wim,
                                               const float* __restrict__ lw,
                                               short* __restrict__ Wre, short* __restrict__ Wim,
                                               short* __restrict__ WL){
  int c = blockIdx.x, tid = threadIdx.x, plane = blockIdx.y;
  int idx = c*C_ + tid;
  if (plane == 0)      Wre[idx] = f2bf(wre[idx]);
  else if (plane == 1) Wim[idx] = f2bf(wim[idx]);
  else                 WL[idx]  = f2bf(lw[idx]);
}

// ---- forward row rFFT via wave-shuffle 64-pt FFT: x2 -> X1t (transposed: [kx*128 + y]) ----
__global__ __launch_bounds__(256) void k_fwd_rows(const float* __restrict__ x2, float2* __restrict__ X1t){
  __shared__ float2 tile[65*33];
  int tid = threadIdx.x;
  int lane = tid & 63, wv = tid >> 6;
  float2 stw[6];
  make_stage_tw(stw, lane);
  float sn128, cs128;
  sincosf(6.283185307179586f*(float)lane/128.0f, &sn128, &cs128);
  int slice = blockIdx.x >> 2;
  int r0 = (blockIdx.x & 3) * 32;
  const float* img = x2 + (size_t)slice*HW_ + (size_t)r0*128;
  #pragma unroll
  for (int i=0; i<8; i++){
    int rr = wv*8 + i;
    // y[m] = x[2m] + i x[2m+1]
    float2 y = *(const float2*)(img + rr*128 + lane*2);
    float2 v = wave_fft64<-1>(y, stw, lane);
    int rbk = brev6(lane);
    float2 Yk; Yk.x = __shfl(v.x, rbk); Yk.y = __shfl(v.y, rbk);
    int rbm = brev6((64 - lane) & 63);
    float2 Ym; Ym.x = __shfl(v.x, rbm); Ym.y = __shfl(v.y, rbm);
    // X[k] = 0.5*(s - i*e^{-i th}*d), th = 2 pi k/128
    float sx = Yk.x + Ym.x, sy = Yk.y - Ym.y;
    float dx = Yk.x - Ym.x, dy = Yk.y + Ym.y;
    tile[lane*33 + rr] = make_float2(0.5f*(sx - sn128*dx + cs128*dy),
                                     0.5f*(sy - cs128*dx - sn128*dy));
    if (lane == 0)
      tile[64*33 + rr] = make_float2(Yk.x - Yk.y, 0.0f);   // X[64] = sum_even - sum_odd
  }
  __syncthreads();
  float2* dst = X1t + (size_t)slice*F_ + r0;
  for (int p = tid; p < 65*32; p += 256){
    int kx = p >> 5, rr = p & 31;
    dst[(size_t)kx*128 + rr] = tile[kx*33 + rr];
  }
}

// ---- forward col FFT (wave-shuffle 128-pt, 2 elems/lane) + ortho scale + band-gate ----
// X1t/Xft layout: [slice][kx*128 + ky]. No FFT LDS, no barriers in the column loop.
__global__ __launch_bounds__(256) void k_fwd_cols_gate(const float2* __restrict__ X1t, float2* __restrict__ Xft,
                                                       const float* __restrict__ counts, const unsigned char* __restrict__ bid_t,
                                                       const float* __restrict__ w1, const float* __restrict__ b1,
                                                       const float* __restrict__ w2, const float* __restrict__ b2,
                                                       float* __restrict__ alpha){
  __shared__ float red[6][256];
  __shared__ float means[6], h[128];
  int tid = threadIdx.x;
  int lane = tid & 63, wv = tid >> 6;
  float2 stw[6];
  make_stage_tw(stw, lane);
  float sn128, cs128;
  sincosf(6.283185307179586f*(float)lane/128.0f, &sn128, &cs128);
  int slice = blockIdx.x;
  const float2* xin = X1t + (size_t)slice*F_;
  float2* xout = Xft + (size_t)slice*F_;
  float acc[6] = {0,0,0,0,0,0};
  for (int kx = wv; kx < 65; kx += 4){
    float4 rv = *(const float4*)(xin + (size_t)kx*128 + (lane<<1));
    float2 a0 = make_float2(rv.x, rv.y), a1 = make_float2(rv.z, rv.w);
    float2 u0, u1;
    redist2(a0, a1, lane, u0, u1);
    // stage 0 (forward): s = u0+u1; d = (u0-u1)*e^{-2pi i lane/128}
    float2 s = make_float2(u0.x+u1.x, u0.y+u1.y);
    float ddx = u0.x-u1.x, ddy = u0.y-u1.y;
    float2 dw = make_float2(ddx*cs128 + ddy*sn128, ddy*cs128 - ddx*sn128);
    float2 v0 = wave_fft64<-1>(s, stw, lane);
    float2 v1 = wave_fft64<-1>(dw, stw, lane);
    int rb = brev6(lane);
    float ex = __shfl(v0.x, rb), ey = __shfl(v0.y, rb);   // X[2*lane]
    float ox = __shfl(v1.x, rb), oy = __shfl(v1.y, rb);   // X[2*lane+1]
    ex *= 0.0078125f; ey *= 0.0078125f;
    ox *= 0.0078125f; oy *= 0.0078125f;
    float4 wvout = make_float4(ex, ey, ox, oy);
    *(float4*)(xout + (size_t)kx*128 + (lane<<1)) = wvout;
    float me = __fsqrt_rn(ex*ex + ey*ey);
    float mo = __fsqrt_rn(ox*ox + oy*oy);
    int be = (int)bid_t[kx*128 + (lane<<1)];
    int bo = (int)bid_t[kx*128 + (lane<<1) + 1];
    #pragma unroll
    for (int n=0;n<6;n++) acc[n] += ((be==n) ? me : 0.0f) + ((bo==n) ? mo : 0.0f);
  }
  #pragma unroll
  for (int n=0;n<6;n++) red[n][tid] = acc[n];
  __syncthreads();
  for (int s=128; s>0; s>>=1){
    if (tid < s){
      #pragma unroll
      for (int n=0;n<6;n++) red[n][tid] += red[n][tid+s];
    }
    __syncthreads();
  }
  if (tid < 6) means[tid] = red[tid][0] / (counts[tid] + 1e-6f);
  __syncthreads();
  if (tid < 128){
    float hv = b1[tid];
    #pragma unroll
    for (int n=0;n<6;n++) hv += means[n]*w1[tid*6+n];
    h[tid] = fmaxf(hv, 0.0f);
  }
  __syncthreads();
  if (tid < 6){
    float o = b2[tid];
    for (int j=0;j<128;j++) o += h[j]*w2[tid*128+j];
    alpha[slice*6 + tid] = sigmoidf_(o);
  }
}

// ---- pack Xft (static 40x72 region) -> Xt planes [b][fp][d] bf16, fp = kx*72+ky ----
__global__ __launch_bounds__(256) void k_xt(const float2* __restrict__ Xft,
                                            short* __restrict__ XtRe, short* __restrict__ XtIm){
  __shared__ short sre[72*130];
  __shared__ short sim[72*130];
  int tid = threadIdx.x;
  int kx = blockIdx.x, d0 = blockIdx.y*128, b = blockIdx.z;
  const float2* xb = Xft + ((size_t)(b*C_ + d0))*F_ + (size_t)kx*128;
  for (int p = tid; p < 72*128; p += 256){
    int d = p / 72, ky = p - d*72;
    float2 v = xb[(size_t)d*F_ + ky];
    sre[ky*130 + d] = f2bf(v.x);
    sim[ky*130 + d] = f2bf(v.y);
  }
  __syncthreads();
  short* dre = XtRe + ((size_t)b*FP_ + (size_t)kx*72)*C_ + d0;
  short* dim_ = XtIm + ((size_t)b*FP_ + (size_t)kx*72)*C_ + d0;
  for (int p = tid; p < 72*128; p += 256){
    int ky = p >> 7, d = p & 127;
    dre[(size_t)ky*C_ + d] = sre[ky*130 + d];
    dim_[(size_t)ky*C_ + d] = sim[ky*130 + d];
  }
}

// ---- MFMA complex channel mix: mappedP[c][fp] = sum_d W[c][d] * X[fp][d] ----
__global__ __launch_bounds__(256) void k_mix_mfma(const short* __restrict__ Wre, const short* __restrict__ Wim,
                                                  const short* __restrict__ XtRe, const short* __restrict__ XtIm,
                                                  const float* __restrict__ kxp, const float* __restrict__ kyp,
                                                  float2* __restrict__ mappedP){
  __shared__ short Are[64][36], Aim[64][36], Bre[64][36], Bim[64][36];
  int tid = threadIdx.x;
  int fp0 = blockIdx.x*64, c0 = blockIdx.y*64, b = blockIdx.z;
  int lane = tid & 63, w = tid >> 6;
  int mt = (w >> 1)*32, nt = (w & 1)*32;
  f32x16 accre = {0.f,0.f,0.f,0.f,0.f,0.f,0.f,0.f,0.f,0.f,0.f,0.f,0.f,0.f,0.f,0.f};
  f32x16 accim = {0.f,0.f,0.f,0.f,0.f,0.f,0.f,0.f,0.f,0.f,0.f,0.f,0.f,0.f,0.f,0.f};
  const short* xrb = XtRe + ((size_t)b*FP_ + fp0)*C_;
  const short* xib = XtIm + ((size_t)b*FP_ + fp0)*C_;
  int row4 = tid >> 2, part = tid & 3;
  for (int kc=0; kc<8; kc++){
    int d0 = kc*32;
    __syncthreads();
    lds_store8(&Are[row4][part*8], *(const bf16x8*)&Wre[(c0+row4)*C_ + d0 + part*8]);
    lds_store8(&Aim[row4][part*8], *(const bf16x8*)&Wim[(c0+row4)*C_ + d0 + part*8]);
    lds_store8(&Bre[row4][part*8], *(const bf16x8*)&xrb[(size_t)row4*C_ + d0 + part*8]);
    lds_store8(&Bim[row4][part*8], *(const bf16x8*)&xib[(size_t)row4*C_ + d0 + part*8]);
    __syncthreads();
    #pragma unroll
    for (int ks=0; ks<2; ks++){
      int koff = ks*16 + (lane>>5)*8;
      bf16x8 are = lds_frag(&Are[mt + (lane&31)][koff]);
      bf16x8 aim = lds_frag(&Aim[mt + (lane&31)][koff]);
      bf16x8 bre = lds_frag(&Bre[nt + (lane&31)][koff]);
      bf16x8 bim = lds_frag(&Bim[nt + (lane&31)][koff]);
      bf16x8 naim;
      { union { bf16x8 v; unsigned u[4]; } t1, t2; t1.v = aim;
        #pragma unroll
        for (int j=0;j<4;j++) t2.u[j] = t1.u[j] ^ 0x80008000u;
        naim = t2.v; }
      accre = __builtin_amdgcn_mfma_f32_32x32x16_bf16(are,  bre, accre, 0,0,0);
      accre = __builtin_amdgcn_mfma_f32_32x32x16_bf16(naim, bim, accre, 0,0,0);
      accim = __builtin_amdgcn_mfma_f32_32x32x16_bf16(are,  bim, accim, 0,0,0);
      accim = __builtin_amdgcn_mfma_f32_32x32x16_bf16(aim,  bre, accim, 0,0,0);
    }
  }
  float rowlim = floorf(sigmoidf_(kxp[0])*128.0f);
  float collim = floorf(sigmoidf_(kyp[0])*65.0f);
  int n = fp0 + nt + (lane & 31);
  int ky = n % 72, kx = n / 72;
  bool live = ((float)ky < rowlim) && ((float)kx < collim);
  #pragma unroll
  for (int reg=0; reg<16; reg++){
    int r = (reg & 3) + 8*(reg >> 2) + 4*(lane >> 5);
    int c = c0 + mt + r;
    if (live)
      mappedP[((size_t)(b*C_ + c))*FP_ + n] = make_float2(accre[reg], accim[reg]);
  }
}

// ---- MFMA pointwise: xcs[c][hw] = sum_d lin_w[c][d] * x[hw][d] + lin_b[c] ----
__global__ __launch_bounds__(256) void k_pw_mfma(const float* __restrict__ x, const short* __restrict__ WL,
                                                  const float* __restrict__ lb, float* __restrict__ xcs){
  __shared__ short As[64][36], Bs[64][36];
  int tid = threadIdx.x;
  int hw0 = blockIdx.x*64, c0 = blockIdx.y*64, b = blockIdx.z;
  int lane = tid & 63, w = tid >> 6;
  int mt = (w >> 1)*32, nt = (w & 1)*32;
  f32x16 acc = {0.f,0.f,0.f,0.f,0.f,0.f,0.f,0.f,0.f,0.f,0.f,0.f,0.f,0.f,0.f,0.f};
  const float* xb = x + ((size_t)b*HW_ + hw0)*C_;
  int row4 = tid >> 2, part = tid & 3;
  for (int kc=0; kc<8; kc++){
    int d0 = kc*32;
    __syncthreads();
    lds_store8(&As[row4][part*8], *(const bf16x8*)&WL[(c0+row4)*C_ + d0 + part*8]);
    {
      const float* src = &xb[(size_t)row4*C_ + d0 + part*8];
      float4 va = *(const float4*)src;
      float4 vb = *(const float4*)(src+4);
      bf16x8 bv;
      bv[0]=f2bf(va.x); bv[1]=f2bf(va.y); bv[2]=f2bf(va.z); bv[3]=f2bf(va.w);
      bv[4]=f2bf(vb.x); bv[5]=f2bf(vb.y); bv[6]=f2bf(vb.z); bv[7]=f2bf(vb.w);
      lds_store8(&Bs[row4][part*8], bv);
    }
    __syncthreads();
    #pragma unroll
    for (int ks=0; ks<2; ks++){
      int koff = ks*16 + (lane>>5)*8;
      bf16x8 a  = lds_frag(&As[mt + (lane&31)][koff]);
      bf16x8 bb = lds_frag(&Bs[nt + (lane&31)][koff]);
      acc = __builtin_amdgcn_mfma_f32_32x32x16_bf16(a, bb, acc, 0,0,0);
    }
  }
  int n = hw0 + nt + (lane & 31);
  #pragma unroll
  for (int reg=0; reg<16; reg++){
    int r = (reg & 3) + 8*(reg >> 2) + 4*(lane >> 5);
    int c = c0 + mt + r;
    xcs[((size_t)(b*C_ + c))*HW_ + n] = acc[reg] + lb[c];
  }
}

// ---- inverse col FFT (wave-shuffle) with fused alpha-blend; in place on Xft -> Y1t ----
__global__ __launch_bounds__(256) void k_inv_cols(float2* __restrict__ XftY, const float2* __restrict__ mappedP,
                                                  const float* __restrict__ alpha, const unsigned char* __restrict__ bid_t,
                                                  const float* __restrict__ kxp, const float* __restrict__ kyp){
  __shared__ float al[6];
  int tid = threadIdx.x;
  int lane = tid & 63, wv = tid >> 6;
  int slice = blockIdx.x;
  float2 stw[6];
  make_stage_tw(stw, lane);
  float sn128, cs128;
  sincosf(6.283185307179586f*(float)lane/128.0f, &sn128, &cs128);
  if (tid < 6) al[tid] = alpha[slice*6 + tid];
  float rowlim = floorf(sigmoidf_(kxp[0])*128.0f);
  float collim = floorf(sigmoidf_(kyp[0])*65.0f);
  __syncthreads();
  float2* xfb = XftY + (size_t)slice*F_;
  const float2* mpb = mappedP + (size_t)slice*FP_;
  for (int kx = wv; kx < 65; kx += 4){
    float4 rv = *(const float4*)(xfb + (size_t)kx*128 + (lane<<1));
    int ky0 = lane << 1;
    float a_e = al[(int)bid_t[kx*128 + ky0]];
    float a_o = al[(int)bid_t[kx*128 + ky0 + 1]];
    bool cok  = ((float)kx < collim);
    bool in_e = cok && ((float)ky0 < rowlim);
    bool in_o = cok && ((float)(ky0+1) < rowlim);
    float2 ve, vo;
    if (in_e){
      float4 mv = *(const float4*)(mpb + (size_t)kx*72 + ky0);
      ve = make_float2(mv.x*a_e, mv.y*a_e);
      vo = in_o ? make_float2(mv.z*a_o, mv.w*a_o)
                : make_float2(rv.z*(1.0f-a_o), rv.w*(1.0f-a_o));
    } else {
      ve = make_float2(rv.x*(1.0f-a_e), rv.y*(1.0f-a_e));
      vo = make_float2(rv.z*(1.0f-a_o), rv.w*(1.0f-a_o));
    }
    float2 u0, u1;
    redist2(ve, vo, lane, u0, u1);
    // stage 0 (inverse): s = u0+u1; d = (u0-u1)*e^{+2pi i lane/128}
    float2 s = make_float2(u0.x+u1.x, u0.y+u1.y);
    float ddx = u0.x-u1.x, ddy = u0.y-u1.y;
    float2 dw = make_float2(ddx*cs128 - ddy*sn128, ddx*sn128 + ddy*cs128);
    float2 v0 = wave_fft64<1>(s, stw, lane);
    float2 v1 = wave_fft64<1>(dw, stw, lane);
    int rb = brev6(lane);
    float4 outv;
    outv.x = __shfl(v0.x, rb); outv.y = __shfl(v0.y, rb);   // z[2*lane]
    outv.z = __shfl(v1.x, rb); outv.w = __shfl(v1.y, rb);   // z[2*lane+1]
    *(float4*)(xfb + (size_t)kx*128 + (lane<<1)) = outv;
  }
}

// ---- inverse row c2r via wave-shuffle 64-pt FFT + fused depthwise 3x3 conv + xcs -> sbuf ----
// Y1t is column-major [kx*128 + y]; staged through an LDS tile for row access.
__global__ __launch_bounds__(256) void k_inv_rows(const float2* __restrict__ Y1t, const float* __restrict__ xcs,
                                                  const float* __restrict__ x2, const float* __restrict__ cw,
                                                  float* __restrict__ sbuf){
  __shared__ float ct[34*128];
  __shared__ float2 ytile[65*33];
  int tid = threadIdx.x;
  int lane = tid & 63, wv = tid >> 6;
  float2 stw[6];
  make_stage_tw(stw, lane);
  float sn128, cs128;
  sincosf(6.283185307179586f*(float)lane/128.0f, &sn128, &cs128);
  int slice = blockIdx.x >> 2;
  int ch = slice & 255;
  int r0 = (blockIdx.x & 3) * 32;
  const float* img = x2 + (size_t)slice*HW_;
  #pragma unroll
  for (int q=0;q<17;q++){
    int p = tid + q*256;
    int row = p >> 7, xx = p & 127;
    int sr = r0 - 1 + row;
    ct[p] = ((unsigned)sr < 128u) ? img[sr*128+xx] : 0.0f;
  }
  const float2* ysrc = Y1t + (size_t)slice*F_ + r0;
  for (int p = tid; p < 65*32; p += 256){
    int kx = p >> 5, rr = p & 31;
    ytile[kx*33 + rr] = ysrc[(size_t)kx*128 + rr];
  }
  float w9[9];
  #pragma unroll
  for (int k=0;k<9;k++) w9[k] = cw[ch*9+k];
  __syncthreads();
  size_t gbase = (size_t)slice*HW_ + (size_t)r0*128;
  #pragma unroll
  for (int i=0;i<8;i++){
    int row = wv*8 + i;
    // Y[k] = 0.5*(X[k]+conj(X[64-k])) + 0.5*i*e^{+i th_k}*(X[k]-conj(X[64-k])), th_k = 2 pi k/128
    float2 a = ytile[lane*33 + row];
    float2 b = ytile[(64-lane)*33 + row];
    if (lane == 0){ a.y = 0.0f; b.y = 0.0f; }   // force Im(X[0]) = Im(X[64]) = 0
    float sx = a.x + b.x, sy = a.y - b.y;
    float dx = a.x - b.x, dy = a.y + b.y;
    float2 yk = make_float2(0.5f*(sx - sn128*dx - cs128*dy),
                            0.5f*(sy + cs128*dx - sn128*dy));
    float2 v = wave_fft64<1>(yk, stw, lane);
    // un-bit-reverse: lane m holds z[m]; x[2m] = Re/64, x[2m+1] = Im/64
    int rbk = brev6(lane);
    float2 z; z.x = __shfl(v.x, rbk); z.y = __shfl(v.y, rbk);
    int xx = lane << 1;
    float c0 = 0.0f, c1 = 0.0f;
    #pragma unroll
    for (int dy2=0; dy2<3; dy2++){
      const float* cr = &ct[(row+dy2)*128];
      float l  = (xx>0)    ? cr[xx-1] : 0.0f;
      float mm = cr[xx];
      float r  = cr[xx+1];
      float rr = (xx<126)  ? cr[xx+2] : 0.0f;
      c0 += l*w9[dy2*3+0] + mm*w9[dy2*3+1] + r*w9[dy2*3+2];
      c1 += mm*w9[dy2*3+0] + r*w9[dy2*3+1] + rr*w9[dy2*3+2];
    }
    size_t g = gbase + (size_t)(row*128 + xx);
    float2 xc = *(const float2*)&xcs[g];
    float2 o;
    o.x = z.x*0.015625f + xc.x + c0;
    o.y = z.y*0.015625f + xc.y + c1;
    *(float2*)&sbuf[g] = o;
  }
}

// ---- LN stats over channels ----
__global__ __launch_bounds__(256) void k_stats(const float* __restrict__ sbuf, float* __restrict__ stats){
  int g = blockIdx.x*256 + threadIdx.x;
  int b = g >> 14, hw = g & 16383;
  const float* p = sbuf + (size_t)b*C_*HW_ + hw;
  float s1 = 0.0f, s2 = 0.0f;
  for (int c=0; c<C_; c++){
    float v = p[(size_t)c*HW_];
    s1 += v; s2 += v*v;
  }
  float mean = s1 * (1.0f/256.0f);
  float var  = s2 * (1.0f/256.0f) - mean*mean;
  stats[g] = mean;
  stats[65536 + g] = 1.0f / sqrtf(var + 1e-5f);
}

// ---- LN apply + cond scale/shift, coalesced transpose to (B,HW,C) ----
__global__ __launch_bounds__(256) void k_apply(const float* __restrict__ sbuf, const float* __restrict__ stats,
                                               const float* __restrict__ timev,
                                               const float* __restrict__ nww, const float* __restrict__ nwb,
                                               const float* __restrict__ nbw, const float* __restrict__ nbb,
                                               float* __restrict__ out){
  __shared__ float tile[64][65];
  __shared__ float wv[64], bv[64], mv[64], rv[64];
  int b = blockIdx.z, c0 = blockIdx.y*64, hw0 = blockIdx.x*64;
  int tid = threadIdx.x;
  if (tid < 64){
    float t = timev[b];
    int c = c0 + tid;
    wv[tid] = t*nww[c] + nwb[c];
    bv[tid] = t*nbw[c] + nbb[c];
    mv[tid] = stats[(b<<14) + hw0 + tid];
    rv[tid] = stats[65536 + (b<<14) + hw0 + tid];
  }
  #pragma unroll
  for (int q=0;q<16;q++){
    int p = tid + q*256;
    int cl = p >> 6, hwl = p & 63;
    tile[cl][hwl] = sbuf[((size_t)(b*C_+c0+cl))*HW_ + hw0 + hwl];
  }
  __syncthreads();
  #pragma unroll
  for (int q=0;q<16;q++){
    int p = tid + q*256;
    int hwl = p >> 6, cl = p & 63;
    float v = tile[cl][hwl];
    out[((size_t)(b*HW_+hw0+hwl))*C_ + c0 + cl] = wv[cl]*((v - mv[hwl])*rv[hwl]) + bv[cl];
  }
}

extern "C" void kernel_launch(void* const* d_in, const int* in_sizes, int n_in,
                              void* d_out, int out_size, void* d_ws, size_t ws_size,
                              hipStream_t stream){
  const float* x      = (const float*)d_in[0];
  const float* timev  = (const float*)d_in[1];
  const float* w_real = (const float*)d_in[2];
  const float* w_imag = (const float*)d_in[3];
  const float* conv_w = (const float*)d_in[4];
  const float* lin_w  = (const float*)d_in[5];
  const float* lin_b  = (const float*)d_in[6];
  const float* mlp_w1 = (const float*)d_in[7];
  const float* mlp_b1 = (const float*)d_in[8];
  const float* mlp_w2 = (const float*)d_in[9];
  const float* mlp_b2 = (const float*)d_in[10];
  const float* norm_ww= (const float*)d_in[11];
  const float* norm_wb= (const float*)d_in[12];
  const float* norm_bw= (const float*)d_in[13];
  const float* norm_bb= (const float*)d_in[14];
  const float* kxp    = (const float*)d_in[15];
  const float* kyp    = (const float*)d_in[16];

  // workspace layout (floats) — total 51,093,600 floats = 194.9 MiB
  float* ws = (float*)d_ws;
  float*  alpha  = ws;                               // 6144
  unsigned char* bid_t = (unsigned char*)(ws + 6144);// 8320 B (transposed band table [kx*128+ky])
  float*  counts = ws + 8224;                        // 64
  float*  stats  = ws + 8288;                        // 131072
  short*  Wre_bf = (short*)(ws + 139360);            // 65536 shorts (32768 floats)
  short*  Wim_bf = (short*)(ws + 172128);            // 65536 shorts
  short*  WL_bf  = (short*)(ws + 204896);            // 65536 shorts
  float*  x2     = ws + 237664;                      // 16,777,216 (live until inv_rows: conv input)
  float2* Xft    = (float2*)(ws + 17014880);         // 17,039,360 floats (Xft transposed, then Y1t in-place)
  float*  CbF    = ws + 34054240;                    // 17,039,360 floats, multi-use:
  float2* X1t    = (float2*)CbF;                     //   X1t (fwd FFT intermediate, dead after fwd_cols_gate)
  short*  XtRe   = (short*)CbF;                      //   then Xt bf16 planes [b][2880][256]
  short*  XtIm   = (short*)(CbF + 1474560);
  float2* mappedP= (float2*)(CbF + 2949120);         //   packed mapped [b][c][2880] (5,898,240 floats)
  float*  sb     = CbF;                              //   then final sum (16,777,216) after inv_cols
  float*  xcs    = (float*)d_out;                    // pointwise output, scratch in d_out
  float*  out    = (float*)d_out;

  k_transpose    <<<dim3(256, 4, B_), dim3(64,16), 0, stream>>>(x, x2);
  k_counts       <<<1, 256, 0, stream>>>(counts, bid_t);
  k_wbf16        <<<dim3(256, 3), 256, 0, stream>>>(w_real, w_imag, lin_w, Wre_bf, Wim_bf, WL_bf);
  k_fwd_rows     <<<4096, 256, 0, stream>>>(x2, X1t);
  k_fwd_cols_gate<<<1024, 256, 0, stream>>>(X1t, Xft, counts, bid_t, mlp_w1, mlp_b1, mlp_w2, mlp_b2, alpha);
  k_xt           <<<dim3(40, 2, B_), 256, 0, stream>>>(Xft, XtRe, XtIm);
  k_pw_mfma      <<<dim3(256, 4, B_), 256, 0, stream>>>(x, WL_bf, lin_b, xcs);
  k_mix_mfma     <<<dim3(45, 4, B_), 256, 0, stream>>>(Wre_bf, Wim_bf, XtRe, XtIm, kxp, kyp, mappedP);
  k_inv_cols     <<<1024, 256, 0, stream>>>(Xft, mappedP, alpha, bid_t, kxp, kyp);
  k_inv_rows     <<<4096, 256, 0, stream>>>((const float2*)Xft, xcs, x2, conv_w, sb);
  k_stats        <<<256, 256, 0, stream>>>(sb, stats);
  k_apply        <<<dim3(256, 4, B_), 256, 0, stream>>>(sb, stats, timev, norm_ww, norm_wb, norm_bw, norm_bb, out);
}

// Round 4
// 430.640 us; speedup vs baseline: 1.3268x; 1.0467x over previous
//
#include <hip/hip_runtime.h>
#include <math.h>

#define B_ 4
#define C_ 256
#define RES_ 128
#define HW_ 16384
#define WF_ 65
#define F_ 8320
#define FP_ 2880   // packed masked-freq grid: 40 cols x 72 rows, fp = kx*72 + ky (covers runtime 36x71)

typedef __attribute__((ext_vector_type(8))) short bf16x8;
typedef __attribute__((ext_vector_type(16))) float f32x16;

__device__ __forceinline__ int brev6(int j){ return (int)(__brev((unsigned)j) >> 26); }

__device__ __forceinline__ short f2bf(float f){
  unsigned u = __float_as_uint(f);
  unsigned r = (u + 0x7FFFu + ((u>>16)&1u)) >> 16;
  return (short)r;
}

__device__ __forceinline__ bf16x8 lds_frag(const short* p){
  union { bf16x8 v; int2 d[2]; } u;
  u.d[0] = *(const int2*)p;
  u.d[1] = *(const int2*)(p+4);
  return u.v;
}
__device__ __forceinline__ void lds_store8(short* p, bf16x8 v){
  union { bf16x8 v; int2 d[2]; } u; u.v = v;
  *(int2*)p = u.d[0]; *(int2*)(p+4) = u.d[1];
}

// ---- band id, bit-exact vs numpy float32 ----
__device__ __forceinline__ int band_of(int row, int col){
  float yy = __fdiv_rn((float)row, 127.0f);
  float xx = __fdiv_rn((float)col, 64.0f);
  float rr = __fsqrt_rn(__fadd_rn(__fmul_rn(yy,yy), __fmul_rn(xx,xx)));
  float rm = __fadd_rn(__fsqrt_rn(2.0f), 1e-8f);
  float rn = __fdiv_rn(rr, rm);
  int b = (int)floorf(__fmul_rn(rn, 6.0f));
  return b > 5 ? 5 : b;
}

__device__ __forceinline__ float sigmoidf_(float v){ return 1.0f/(1.0f+expf(-v)); }

// ---- wave-synchronous 64-pt radix-2 DIF FFT, one complex value per lane ----
// Output bit-reversed across lanes: result for index r lives at lane brev6(r).
template<int SGN>
__device__ __forceinline__ float2 wave_fft64(float2 v, const float2* stw, int lane){
  #pragma unroll
  for (int s=0; s<6; s++){
    int H = 32 >> s;
    float ox = __shfl_xor(v.x, H);
    float oy = __shfl_xor(v.y, H);
    bool hi = (lane & H) != 0;
    float2 w = stw[s];
    float ws = (SGN < 0) ? -w.y : w.y;
    float sx = v.x + ox, sy = v.y + oy;
    float dx = ox - v.x, dy = oy - v.y;   // (a - b) on the hi lane
    float rx = dx*w.x - dy*ws;
    float ry = dx*ws + dy*w.x;
    v.x = hi ? rx : sx;
    v.y = hi ? ry : sy;
  }
  return v;
}

// per-lane stage twiddles: identical float values to a 128-entry table at even indices
__device__ __forceinline__ void make_stage_tw(float2* stw, int lane){
  #pragma unroll
  for (int s=0; s<6; s++){
    int H = 32 >> s;
    int t = (lane & (H-1)) << s;
    float sn, cs;
    sincosf(6.283185307179586f*(float)t/64.0f, &sn, &cs);
    stw[s] = make_float2(cs, sn);
  }
}

// redistribute (val[2l], val[2l+1]) per lane -> u0 = val[l], u1 = val[l+64]
__device__ __forceinline__ void redist2(float2 a0, float2 a1, int lane, float2& u0, float2& u1){
  int s0 = lane >> 1, s1 = s0 + 32;
  bool odd = (lane & 1) != 0;
  float t0x = __shfl(a0.x, s0), t0y = __shfl(a0.y, s0);
  float t1x = __shfl(a1.x, s0), t1y = __shfl(a1.y, s0);
  u0 = odd ? make_float2(t1x, t1y) : make_float2(t0x, t0y);
  float q0x = __shfl(a0.x, s1), q0y = __shfl(a0.y, s1);
  float q1x = __shfl(a1.x, s1), q1y = __shfl(a1.y, s1);
  u1 = odd ? make_float2(q1x, q1y) : make_float2(q0x, q0y);
}

// ---- (B,HW,C) -> (B,C,HW) transpose ----
__global__ __launch_bounds__(1024) void k_transpose(const float* __restrict__ x, float* __restrict__ x2){
  __shared__ float tile[64][65];
  int b = blockIdx.z;
  int hw0 = blockIdx.x*64, c0 = blockIdx.y*64;
  int tx = threadIdx.x, ty = threadIdx.y;
  #pragma unroll
  for (int i=0;i<4;i++){
    int hw = hw0 + ty + i*16;
    tile[ty+i*16][tx] = x[((size_t)b*HW_ + hw)*C_ + c0 + tx];
  }
  __syncthreads();
  #pragma unroll
  for (int i=0;i<4;i++){
    int c = c0 + ty + i*16;
    x2[((size_t)b*C_ + c)*HW_ + hw0 + tx] = tile[tx][ty+i*16];
  }
}

// ---- counts + transposed band-id table: bid_t[kx*128 + ky] ----
__global__ __launch_bounds__(256) void k_counts(float* __restrict__ counts, unsigned char* __restrict__ bid_t){
  int tid = threadIdx.x;
  float acc[6] = {0,0,0,0,0,0};
  for (int p = tid; p < F_; p += 256){
    int kx = p >> 7, ky = p & 127;
    int bnd = band_of(ky, kx);
    bid_t[p] = (unsigned char)bnd;
    #pragma unroll
    for (int n=0;n<6;n++) acc[n] += (bnd==n) ? 1.0f : 0.0f;
  }
  __shared__ float red[6][256];
  #pragma unroll
  for (int n=0;n<6;n++) red[n][tid] = acc[n];
  __syncthreads();
  for (int s=128; s>0; s>>=1){
    if (tid < s){
      #pragma unroll
      for (int n=0;n<6;n++) red[n][tid] += red[n][tid+s];
    }
    __syncthreads();
  }
  if (tid < 6) counts[tid] = fmaxf(red[tid][0], 1.0f);
}

// ---- convert W matrices to bf16 planes ----
__global__ __launch_bounds__(256) void k_wbf16(const float* __restrict__ wre, const float* __restrict__ wim,
                                               const float* __restrict__ lw,
                                               short* __restrict__ Wre, short* __restrict__ Wim,
                                               short* __restrict__ WL){
  int c = blockIdx.x, tid = threadIdx.x, plane = blockIdx.y;
  int idx = c*C_ + tid;
  if (plane == 0)      Wre[idx] = f2bf(wre[idx]);
  else if (plane == 1) Wim[idx] = f2bf(wim[idx]);
  else                 WL[idx]  = f2bf(lw[idx]);
}

// ---- forward row rFFT via wave-shuffle 64-pt FFT: x2 -> X1t (transposed: [kx*128 + y]) ----
__global__ __launch_bounds__(256) void k_fwd_rows(const float* __restrict__ x2, float2* __restrict__ X1t){
  __shared__ float2 tile[65*33];
  int tid = threadIdx.x;
  int lane = tid & 63, wv = tid >> 6;
  float2 stw[6];
  make_stage_tw(stw, lane);
  float sn128, cs128;
  sincosf(6.283185307179586f*(float)lane/128.0f, &sn128, &cs128);
  int slice = blockIdx.x >> 2;
  int r0 = (blockIdx.x & 3) * 32;
  const float* img = x2 + (size_t)slice*HW_ + (size_t)r0*128;
  #pragma unroll
  for (int i=0; i<8; i++){
    int rr = wv*8 + i;
    // y[m] = x[2m] + i x[2m+1]
    float2 y = *(const float2*)(img + rr*128 + lane*2);
    float2 v = wave_fft64<-1>(y, stw, lane);
    int rbk = brev6(lane);
    float2 Yk; Yk.x = __shfl(v.x, rbk); Yk.y = __shfl(v.y, rbk);
    int rbm = brev6((64 - lane) & 63);
    float2 Ym; Ym.x = __shfl(v.x, rbm); Ym.y = __shfl(v.y, rbm);
    // X[k] = 0.5*(s - i*e^{-i th}*d), th = 2 pi k/128
    float sx = Yk.x + Ym.x, sy = Yk.y - Ym.y;
    float dx = Yk.x - Ym.x, dy = Yk.y + Ym.y;
    tile[lane*33 + rr] = make_float2(0.5f*(sx - sn128*dx + cs128*dy),
                                     0.5f*(sy - cs128*dx - sn128*dy));
    if (lane == 0)
      tile[64*33 + rr] = make_float2(Yk.x - Yk.y, 0.0f);   // X[64] = sum_even - sum_odd
  }
  __syncthreads();
  float2* dst = X1t + (size_t)slice*F_ + r0;
  for (int p = tid; p < 65*32; p += 256){
    int kx = p >> 5, rr = p & 31;
    dst[(size_t)kx*128 + rr] = tile[kx*33 + rr];
  }
}

// ---- forward col FFT (wave-shuffle 128-pt, 2 elems/lane) + ortho scale + band-gate ----
// X1t/Xft layout: [slice][kx*128 + ky]. No FFT LDS, no barriers in the column loop.
__global__ __launch_bounds__(256) void k_fwd_cols_gate(const float2* __restrict__ X1t, float2* __restrict__ Xft,
                                                       const float* __restrict__ counts, const unsigned char* __restrict__ bid_t,
                                                       const float* __restrict__ w1, const float* __restrict__ b1,
                                                       const float* __restrict__ w2, const float* __restrict__ b2,
                                                       float* __restrict__ alpha){
  __shared__ float red[6][256];
  __shared__ float means[6], h[128];
  int tid = threadIdx.x;
  int lane = tid & 63, wv = tid >> 6;
  float2 stw[6];
  make_stage_tw(stw, lane);
  float sn128, cs128;
  sincosf(6.283185307179586f*(float)lane/128.0f, &sn128, &cs128);
  int slice = blockIdx.x;
  const float2* xin = X1t + (size_t)slice*F_;
  float2* xout = Xft + (size_t)slice*F_;
  float acc[6] = {0,0,0,0,0,0};
  for (int kx = wv; kx < 65; kx += 4){
    float4 rv = *(const float4*)(xin + (size_t)kx*128 + (lane<<1));
    float2 a0 = make_float2(rv.x, rv.y), a1 = make_float2(rv.z, rv.w);
    float2 u0, u1;
    redist2(a0, a1, lane, u0, u1);
    // stage 0 (forward): s = u0+u1; d = (u0-u1)*e^{-2pi i lane/128}
    float2 s = make_float2(u0.x+u1.x, u0.y+u1.y);
    float ddx = u0.x-u1.x, ddy = u0.y-u1.y;
    float2 dw = make_float2(ddx*cs128 + ddy*sn128, ddy*cs128 - ddx*sn128);
    float2 v0 = wave_fft64<-1>(s, stw, lane);
    float2 v1 = wave_fft64<-1>(dw, stw, lane);
    int rb = brev6(lane);
    float ex = __shfl(v0.x, rb), ey = __shfl(v0.y, rb);   // X[2*lane]
    float ox = __shfl(v1.x, rb), oy = __shfl(v1.y, rb);   // X[2*lane+1]
    ex *= 0.0078125f; ey *= 0.0078125f;
    ox *= 0.0078125f; oy *= 0.0078125f;
    float4 wvout = make_float4(ex, ey, ox, oy);
    *(float4*)(xout + (size_t)kx*128 + (lane<<1)) = wvout;
    float me = __fsqrt_rn(ex*ex + ey*ey);
    float mo = __fsqrt_rn(ox*ox + oy*oy);
    int be = (int)bid_t[kx*128 + (lane<<1)];
    int bo = (int)bid_t[kx*128 + (lane<<1) + 1];
    #pragma unroll
    for (int n=0;n<6;n++) acc[n] += ((be==n) ? me : 0.0f) + ((bo==n) ? mo : 0.0f);
  }
  #pragma unroll
  for (int n=0;n<6;n++) red[n][tid] = acc[n];
  __syncthreads();
  for (int s=128; s>0; s>>=1){
    if (tid < s){
      #pragma unroll
      for (int n=0;n<6;n++) red[n][tid] += red[n][tid+s];
    }
    __syncthreads();
  }
  if (tid < 6) means[tid] = red[tid][0] / (counts[tid] + 1e-6f);
  __syncthreads();
  if (tid < 128){
    float hv = b1[tid];
    #pragma unroll
    for (int n=0;n<6;n++) hv += means[n]*w1[tid*6+n];
    h[tid] = fmaxf(hv, 0.0f);
  }
  __syncthreads();
  if (tid < 6){
    float o = b2[tid];
    for (int j=0;j<128;j++) o += h[j]*w2[tid*128+j];
    alpha[slice*6 + tid] = sigmoidf_(o);
  }
}

// ---- pack Xft (static 40x72 region) -> Xt planes [b][fp][d] bf16, fp = kx*72+ky ----
__global__ __launch_bounds__(256) void k_xt(const float2* __restrict__ Xft,
                                            short* __restrict__ XtRe, short* __restrict__ XtIm){
  __shared__ short sre[72*130];
  __shared__ short sim[72*130];
  int tid = threadIdx.x;
  int kx = blockIdx.x, d0 = blockIdx.y*128, b = blockIdx.z;
  const float2* xb = Xft + ((size_t)(b*C_ + d0))*F_ + (size_t)kx*128;
  for (int p = tid; p < 72*128; p += 256){
    int d = p / 72, ky = p - d*72;
    float2 v = xb[(size_t)d*F_ + ky];
    sre[ky*130 + d] = f2bf(v.x);
    sim[ky*130 + d] = f2bf(v.y);
  }
  __syncthreads();
  short* dre = XtRe + ((size_t)b*FP_ + (size_t)kx*72)*C_ + d0;
  short* dim_ = XtIm + ((size_t)b*FP_ + (size_t)kx*72)*C_ + d0;
  for (int p = tid; p < 72*128; p += 256){
    int ky = p >> 7, d = p & 127;
    dre[(size_t)ky*C_ + d] = sre[ky*130 + d];
    dim_[(size_t)ky*C_ + d] = sim[ky*130 + d];
  }
}

// ---- MFMA complex channel mix: mappedP[c][fp] = sum_d W[c][d] * X[fp][d] ----
__global__ __launch_bounds__(256) void k_mix_mfma(const short* __restrict__ Wre, const short* __restrict__ Wim,
                                                  const short* __restrict__ XtRe, const short* __restrict__ XtIm,
                                                  const float* __restrict__ kxp, const float* __restrict__ kyp,
                                                  float2* __restrict__ mappedP){
  __shared__ short Are[64][36], Aim[64][36], Bre[64][36], Bim[64][36];
  int tid = threadIdx.x;
  int fp0 = blockIdx.x*64, c0 = blockIdx.y*64, b = blockIdx.z;
  int lane = tid & 63, w = tid >> 6;
  int mt = (w >> 1)*32, nt = (w & 1)*32;
  f32x16 accre = {0.f,0.f,0.f,0.f,0.f,0.f,0.f,0.f,0.f,0.f,0.f,0.f,0.f,0.f,0.f,0.f};
  f32x16 accim = {0.f,0.f,0.f,0.f,0.f,0.f,0.f,0.f,0.f,0.f,0.f,0.f,0.f,0.f,0.f,0.f};
  const short* xrb = XtRe + ((size_t)b*FP_ + fp0)*C_;
  const short* xib = XtIm + ((size_t)b*FP_ + fp0)*C_;
  int row4 = tid >> 2, part = tid & 3;
  for (int kc=0; kc<8; kc++){
    int d0 = kc*32;
    __syncthreads();
    lds_store8(&Are[row4][part*8], *(const bf16x8*)&Wre[(c0+row4)*C_ + d0 + part*8]);
    lds_store8(&Aim[row4][part*8], *(const bf16x8*)&Wim[(c0+row4)*C_ + d0 + part*8]);
    lds_store8(&Bre[row4][part*8], *(const bf16x8*)&xrb[(size_t)row4*C_ + d0 + part*8]);
    lds_store8(&Bim[row4][part*8], *(const bf16x8*)&xib[(size_t)row4*C_ + d0 + part*8]);
    __syncthreads();
    #pragma unroll
    for (int ks=0; ks<2; ks++){
      int koff = ks*16 + (lane>>5)*8;
      bf16x8 are = lds_frag(&Are[mt + (lane&31)][koff]);
      bf16x8 aim = lds_frag(&Aim[mt + (lane&31)][koff]);
      bf16x8 bre = lds_frag(&Bre[nt + (lane&31)][koff]);
      bf16x8 bim = lds_frag(&Bim[nt + (lane&31)][koff]);
      bf16x8 naim;
      { union { bf16x8 v; unsigned u[4]; } t1, t2; t1.v = aim;
        #pragma unroll
        for (int j=0;j<4;j++) t2.u[j] = t1.u[j] ^ 0x80008000u;
        naim = t2.v; }
      accre = __builtin_amdgcn_mfma_f32_32x32x16_bf16(are,  bre, accre, 0,0,0);
      accre = __builtin_amdgcn_mfma_f32_32x32x16_bf16(naim, bim, accre, 0,0,0);
      accim = __builtin_amdgcn_mfma_f32_32x32x16_bf16(are,  bim, accim, 0,0,0);
      accim = __builtin_amdgcn_mfma_f32_32x32x16_bf16(aim,  bre, accim, 0,0,0);
    }
  }
  float rowlim = floorf(sigmoidf_(kxp[0])*128.0f);
  float collim = floorf(sigmoidf_(kyp[0])*65.0f);
  int n = fp0 + nt + (lane & 31);
  int ky = n % 72, kx = n / 72;
  bool live = ((float)ky < rowlim) && ((float)kx < collim);
  #pragma unroll
  for (int reg=0; reg<16; reg++){
    int r = (reg & 3) + 8*(reg >> 2) + 4*(lane >> 5);
    int c = c0 + mt + r;
    if (live)
      mappedP[((size_t)(b*C_ + c))*FP_ + n] = make_float2(accre[reg], accim[reg]);
  }
}

// ---- MFMA pointwise: xcs[c][hw] = sum_d lin_w[c][d] * x[hw][d] + lin_b[c] ----
__global__ __launch_bounds__(256) void k_pw_mfma(const float* __restrict__ x, const short* __restrict__ WL,
                                                  const float* __restrict__ lb, float* __restrict__ xcs){
  __shared__ short As[64][36], Bs[64][36];
  int tid = threadIdx.x;
  int hw0 = blockIdx.x*64, c0 = blockIdx.y*64, b = blockIdx.z;
  int lane = tid & 63, w = tid >> 6;
  int mt = (w >> 1)*32, nt = (w & 1)*32;
  f32x16 acc = {0.f,0.f,0.f,0.f,0.f,0.f,0.f,0.f,0.f,0.f,0.f,0.f,0.f,0.f,0.f,0.f};
  const float* xb = x + ((size_t)b*HW_ + hw0)*C_;
  int row4 = tid >> 2, part = tid & 3;
  for (int kc=0; kc<8; kc++){
    int d0 = kc*32;
    __syncthreads();
    lds_store8(&As[row4][part*8], *(const bf16x8*)&WL[(c0+row4)*C_ + d0 + part*8]);
    {
      const float* src = &xb[(size_t)row4*C_ + d0 + part*8];
      float4 va = *(const float4*)src;
      float4 vb = *(const float4*)(src+4);
      bf16x8 bv;
      bv[0]=f2bf(va.x); bv[1]=f2bf(va.y); bv[2]=f2bf(va.z); bv[3]=f2bf(va.w);
      bv[4]=f2bf(vb.x); bv[5]=f2bf(vb.y); bv[6]=f2bf(vb.z); bv[7]=f2bf(vb.w);
      lds_store8(&Bs[row4][part*8], bv);
    }
    __syncthreads();
    #pragma unroll
    for (int ks=0; ks<2; ks++){
      int koff = ks*16 + (lane>>5)*8;
      bf16x8 a  = lds_frag(&As[mt + (lane&31)][koff]);
      bf16x8 bb = lds_frag(&Bs[nt + (lane&31)][koff]);
      acc = __builtin_amdgcn_mfma_f32_32x32x16_bf16(a, bb, acc, 0,0,0);
    }
  }
  int n = hw0 + nt + (lane & 31);
  #pragma unroll
  for (int reg=0; reg<16; reg++){
    int r = (reg & 3) + 8*(reg >> 2) + 4*(lane >> 5);
    int c = c0 + mt + r;
    xcs[((size_t)(b*C_ + c))*HW_ + n] = acc[reg] + lb[c];
  }
}

// ---- inverse col FFT (wave-shuffle) with fused alpha-blend; in place on Xft -> Y1t ----
__global__ __launch_bounds__(256) void k_inv_cols(float2* __restrict__ XftY, const float2* __restrict__ mappedP,
                                                  const float* __restrict__ alpha, const unsigned char* __restrict__ bid_t,
                                                  const float* __restrict__ kxp, const float* __restrict__ kyp){
  __shared__ float al[6];
  int tid = threadIdx.x;
  int lane = tid & 63, wv = tid >> 6;
  int slice = blockIdx.x;
  float2 stw[6];
  make_stage_tw(stw, lane);
  float sn128, cs128;
  sincosf(6.283185307179586f*(float)lane/128.0f, &sn128, &cs128);
  if (tid < 6) al[tid] = alpha[slice*6 + tid];
  float rowlim = floorf(sigmoidf_(kxp[0])*128.0f);
  float collim = floorf(sigmoidf_(kyp[0])*65.0f);
  __syncthreads();
  float2* xfb = XftY + (size_t)slice*F_;
  const float2* mpb = mappedP + (size_t)slice*FP_;
  for (int kx = wv; kx < 65; kx += 4){
    float4 rv = *(const float4*)(xfb + (size_t)kx*128 + (lane<<1));
    int ky0 = lane << 1;
    float a_e = al[(int)bid_t[kx*128 + ky0]];
    float a_o = al[(int)bid_t[kx*128 + ky0 + 1]];
    bool cok  = ((float)kx < collim);
    bool in_e = cok && ((float)ky0 < rowlim);
    bool in_o = cok && ((float)(ky0+1) < rowlim);
    float2 ve, vo;
    if (in_e){
      float4 mv = *(const float4*)(mpb + (size_t)kx*72 + ky0);
      ve = make_float2(mv.x*a_e, mv.y*a_e);
      vo = in_o ? make_float2(mv.z*a_o, mv.w*a_o)
                : make_float2(rv.z*(1.0f-a_o), rv.w*(1.0f-a_o));
    } else {
      ve = make_float2(rv.x*(1.0f-a_e), rv.y*(1.0f-a_e));
      vo = make_float2(rv.z*(1.0f-a_o), rv.w*(1.0f-a_o));
    }
    float2 u0, u1;
    redist2(ve, vo, lane, u0, u1);
    // stage 0 (inverse): s = u0+u1; d = (u0-u1)*e^{+2pi i lane/128}
    float2 s = make_float2(u0.x+u1.x, u0.y+u1.y);
    float ddx = u0.x-u1.x, ddy = u0.y-u1.y;
    float2 dw = make_float2(ddx*cs128 - ddy*sn128, ddx*sn128 + ddy*cs128);
    float2 v0 = wave_fft64<1>(s, stw, lane);
    float2 v1 = wave_fft64<1>(dw, stw, lane);
    int rb = brev6(lane);
    float4 outv;
    outv.x = __shfl(v0.x, rb); outv.y = __shfl(v0.y, rb);   // z[2*lane]
    outv.z = __shfl(v1.x, rb); outv.w = __shfl(v1.y, rb);   // z[2*lane+1]
    *(float4*)(xfb + (size_t)kx*128 + (lane<<1)) = outv;
  }
}

// ---- inverse row c2r via wave-shuffle 64-pt FFT + fused depthwise 3x3 conv + xcs -> sbuf ----
// conv input comes straight from global via per-lane register windows + wave shuffles:
// lane l owns cols 2l,2l+1; neighbors via shfl_up/down. No conv LDS tile.
__global__ __launch_bounds__(256,6) void k_inv_rows(const float2* __restrict__ Y1t, const float* __restrict__ xcs,
                                                    const float* __restrict__ x2, const float* __restrict__ cw,
                                                    float* __restrict__ sbuf){
  __shared__ float2 ytile[65*33];
  int tid = threadIdx.x;
  int lane = tid & 63, wv = tid >> 6;
  float2 stw[6];
  make_stage_tw(stw, lane);
  float sn128, cs128;
  sincosf(6.283185307179586f*(float)lane/128.0f, &sn128, &cs128);
  int slice = blockIdx.x >> 2;
  int ch = slice & 255;
  int r0 = (blockIdx.x & 3) * 32;
  const float* img = x2 + (size_t)slice*HW_;
  // preload all 10 conv rows for this wave's 8-row strip (issued before LDS staging -> latency overlap)
  int base = r0 + wv*8;
  float2 rows[10];
  #pragma unroll
  for (int i=0;i<10;i++){
    int gr = base - 1 + i;
    rows[i] = ((unsigned)gr < 128u) ? *(const float2*)(img + (size_t)gr*128 + (lane<<1))
                                    : make_float2(0.0f, 0.0f);
  }
  const float2* ysrc = Y1t + (size_t)slice*F_ + r0;
  for (int p = tid; p < 65*32; p += 256){
    int kx = p >> 5, rr = p & 31;
    ytile[kx*33 + rr] = ysrc[(size_t)kx*128 + rr];
  }
  float w9[9];
  #pragma unroll
  for (int k=0;k<9;k++) w9[k] = cw[ch*9+k];
  __syncthreads();
  size_t gbase = (size_t)slice*HW_ + (size_t)r0*128;
  #pragma unroll
  for (int i=0;i<8;i++){
    int row = wv*8 + i;
    // Y[k] = 0.5*(X[k]+conj(X[64-k])) + 0.5*i*e^{+i th_k}*(X[k]-conj(X[64-k])), th_k = 2 pi k/128
    float2 a = ytile[lane*33 + row];
    float2 b = ytile[(64-lane)*33 + row];
    if (lane == 0){ a.y = 0.0f; b.y = 0.0f; }   // force Im(X[0]) = Im(X[64]) = 0
    float sx = a.x + b.x, sy = a.y - b.y;
    float dx = a.x - b.x, dy = a.y + b.y;
    float2 yk = make_float2(0.5f*(sx - sn128*dx - cs128*dy),
                            0.5f*(sy + cs128*dx - sn128*dy));
    float2 v = wave_fft64<1>(yk, stw, lane);
    // un-bit-reverse: lane m holds z[m]; x[2m] = Re/64, x[2m+1] = Im/64
    int rbk = brev6(lane);
    float2 z; z.x = __shfl(v.x, rbk); z.y = __shfl(v.y, rbk);
    int xx = lane << 1;
    float c0 = 0.0f, c1 = 0.0f;
    #pragma unroll
    for (int dy2=0; dy2<3; dy2++){
      float2 cv = rows[i + dy2];
      float l = __shfl_up(cv.y, 1);
      if (lane == 0) l = 0.0f;                 // col -1
      float r = __shfl_down(cv.x, 1);
      if (lane == 63) r = 0.0f;                // col 128
      c0 += l*w9[dy2*3+0] + cv.x*w9[dy2*3+1] + cv.y*w9[dy2*3+2];
      c1 += cv.x*w9[dy2*3+0] + cv.y*w9[dy2*3+1] + r*w9[dy2*3+2];
    }
    size_t g = gbase + (size_t)(row*128 + xx);
    float2 xc = *(const float2*)&xcs[g];
    float2 o;
    o.x = z.x*0.015625f + xc.x + c0;
    o.y = z.y*0.015625f + xc.y + c1;
    *(float2*)&sbuf[g] = o;
  }
}

// ---- LN stats over channels ----
__global__ __launch_bounds__(256) void k_stats(const float* __restrict__ sbuf, float* __restrict__ stats){
  int g = blockIdx.x*256 + threadIdx.x;
  int b = g >> 14, hw = g & 16383;
  const float* p = sbuf + (size_t)b*C_*HW_ + hw;
  float s1 = 0.0f, s2 = 0.0f;
  for (int c=0; c<C_; c++){
    float v = p[(size_t)c*HW_];
    s1 += v; s2 += v*v;
  }
  float mean = s1 * (1.0f/256.0f);
  float var  = s2 * (1.0f/256.0f) - mean*mean;
  stats[g] = mean;
  stats[65536 + g] = 1.0f / sqrtf(var + 1e-5f);
}

// ---- LN apply + cond scale/shift, coalesced transpose to (B,HW,C) ----
__global__ __launch_bounds__(256) void k_apply(const float* __restrict__ sbuf, const float* __restrict__ stats,
                                               const float* __restrict__ timev,
                                               const float* __restrict__ nww, const float* __restrict__ nwb,
                                               const float* __restrict__ nbw, const float* __restrict__ nbb,
                                               float* __restrict__ out){
  __shared__ float tile[64][65];
  __shared__ float wv[64], bv[64], mv[64], rv[64];
  int b = blockIdx.z, c0 = blockIdx.y*64, hw0 = blockIdx.x*64;
  int tid = threadIdx.x;
  if (tid < 64){
    float t = timev[b];
    int c = c0 + tid;
    wv[tid] = t*nww[c] + nwb[c];
    bv[tid] = t*nbw[c] + nbb[c];
    mv[tid] = stats[(b<<14) + hw0 + tid];
    rv[tid] = stats[65536 + (b<<14) + hw0 + tid];
  }
  #pragma unroll
  for (int q=0;q<16;q++){
    int p = tid + q*256;
    int cl = p >> 6, hwl = p & 63;
    tile[cl][hwl] = sbuf[((size_t)(b*C_+c0+cl))*HW_ + hw0 + hwl];
  }
  __syncthreads();
  #pragma unroll
  for (int q=0;q<16;q++){
    int p = tid + q*256;
    int hwl = p >> 6, cl = p & 63;
    float v = tile[cl][hwl];
    out[((size_t)(b*HW_+hw0+hwl))*C_ + c0 + cl] = wv[cl]*((v - mv[hwl])*rv[hwl]) + bv[cl];
  }
}

extern "C" void kernel_launch(void* const* d_in, const int* in_sizes, int n_in,
                              void* d_out, int out_size, void* d_ws, size_t ws_size,
                              hipStream_t stream){
  const float* x      = (const float*)d_in[0];
  const float* timev  = (const float*)d_in[1];
  const float* w_real = (const float*)d_in[2];
  const float* w_imag = (const float*)d_in[3];
  const float* conv_w = (const float*)d_in[4];
  const float* lin_w  = (const float*)d_in[5];
  const float* lin_b  = (const float*)d_in[6];
  const float* mlp_w1 = (const float*)d_in[7];
  const float* mlp_b1 = (const float*)d_in[8];
  const float* mlp_w2 = (const float*)d_in[9];
  const float* mlp_b2 = (const float*)d_in[10];
  const float* norm_ww= (const float*)d_in[11];
  const float* norm_wb= (const float*)d_in[12];
  const float* norm_bw= (const float*)d_in[13];
  const float* norm_bb= (const float*)d_in[14];
  const float* kxp    = (const float*)d_in[15];
  const float* kyp    = (const float*)d_in[16];

  // workspace layout (floats) — total 51,093,600 floats = 194.9 MiB
  float* ws = (float*)d_ws;
  float*  alpha  = ws;                               // 6144
  unsigned char* bid_t = (unsigned char*)(ws + 6144);// 8320 B (transposed band table [kx*128+ky])
  float*  counts = ws + 8224;                        // 64
  float*  stats  = ws + 8288;                        // 131072
  short*  Wre_bf = (short*)(ws + 139360);            // 65536 shorts (32768 floats)
  short*  Wim_bf = (short*)(ws + 172128);            // 65536 shorts
  short*  WL_bf  = (short*)(ws + 204896);            // 65536 shorts
  float*  x2     = ws + 237664;                      // 16,777,216 (live until inv_rows: conv input)
  float2* Xft    = (float2*)(ws + 17014880);         // 17,039,360 floats (Xft transposed, then Y1t in-place)
  float*  CbF    = ws + 34054240;                    // 17,039,360 floats, multi-use:
  float2* X1t    = (float2*)CbF;                     //   X1t (fwd FFT intermediate, dead after fwd_cols_gate)
  short*  XtRe   = (short*)CbF;                      //   then Xt bf16 planes [b][2880][256]
  short*  XtIm   = (short*)(CbF + 1474560);
  float2* mappedP= (float2*)(CbF + 2949120);         //   packed mapped [b][c][2880] (5,898,240 floats)
  float*  sb     = CbF;                              //   then final sum (16,777,216) after inv_cols
  float*  xcs    = (float*)d_out;                    // pointwise output, scratch in d_out
  float*  out    = (float*)d_out;

  k_transpose    <<<dim3(256, 4, B_), dim3(64,16), 0, stream>>>(x, x2);
  k_counts       <<<1, 256, 0, stream>>>(counts, bid_t);
  k_wbf16        <<<dim3(256, 3), 256, 0, stream>>>(w_real, w_imag, lin_w, Wre_bf, Wim_bf, WL_bf);
  k_fwd_rows     <<<4096, 256, 0, stream>>>(x2, X1t);
  k_fwd_cols_gate<<<1024, 256, 0, stream>>>(X1t, Xft, counts, bid_t, mlp_w1, mlp_b1, mlp_w2, mlp_b2, alpha);
  k_xt           <<<dim3(40, 2, B_), 256, 0, stream>>>(Xft, XtRe, XtIm);
  k_pw_mfma      <<<dim3(256, 4, B_), 256, 0, stream>>>(x, WL_bf, lin_b, xcs);
  k_mix_mfma     <<<dim3(45, 4, B_), 256, 0, stream>>>(Wre_bf, Wim_bf, XtRe, XtIm, kxp, kyp, mappedP);
  k_inv_cols     <<<1024, 256, 0, stream>>>(Xft, mappedP, alpha, bid_t, kxp, kyp);
  k_inv_rows     <<<4096, 256, 0, stream>>>((const float2*)Xft, xcs, x2, conv_w, sb);
  k_stats        <<<256, 256, 0, stream>>>(sb, stats);
  k_apply        <<<dim3(256, 4, B_), 256, 0, stream>>>(sb, stats, timev, norm_ww, norm_wb, norm_bw, norm_bb, out);
}